// Round 12
// baseline (419.696 us; speedup 1.0000x reference)
//
#include <hip/hip_runtime.h>
#include <hip/hip_bf16.h>
#include <math.h>

#define B_  4
#define T_  2048
#define D_  1024
#define H_  16
#define HD_ 64
#define M_  8192   // B_*T_

typedef __attribute__((ext_vector_type(8))) short bf16x8;
typedef __attribute__((ext_vector_type(4))) float f32x4;

static __device__ __forceinline__ unsigned short f2bf(float f){
    unsigned int u = __float_as_uint(f);
    unsigned int r = u + 0x7FFFu + ((u >> 16) & 1u);   // RNE
    return (unsigned short)(r >> 16);
}
static __device__ __forceinline__ float bfbits2f(unsigned short s){
    return __uint_as_float(((unsigned int)s) << 16);
}
static __device__ __forceinline__ void gload_lds16(const void* g, void* l){
    __builtin_amdgcn_global_load_lds(
        (const __attribute__((address_space(1))) unsigned int*)g,
        (__attribute__((address_space(3))) unsigned int*)l, 16, 0, 0);
}

union U16x16 { unsigned short us[16]; uint4 q[2]; };

// ---------------------------------------------------------------------------
// prep_x2: x fp32 -> xh (bf16 hi) + xl (bf16 residual). 16 el/thread.
// ---------------------------------------------------------------------------
__global__ __launch_bounds__(256) void prep_x2(
    const float* __restrict__ x,
    unsigned short* __restrict__ xh, unsigned short* __restrict__ xl)
{
    const size_t i = ((size_t)blockIdx.x*256 + threadIdx.x)*16;
    U16x16 uh, ul;
#pragma unroll
    for (int j=0;j<16;j+=4){
        float4 f = *(const float4*)(x+i+j);
        float v[4] = {f.x,f.y,f.z,f.w};
#pragma unroll
        for (int k=0;k<4;k++){
            unsigned short hb = f2bf(v[k]);
            uh.us[j+k] = hb;
            ul.us[j+k] = f2bf(v[k] - bfbits2f(hb));
        }
    }
    *(uint4*)(xh+i)   = uh.q[0]; *(uint4*)(xh+i+8) = uh.q[1];
    *(uint4*)(xl+i)   = ul.q[0]; *(uint4*)(xl+i+8) = ul.q[1];
}

// ---------------------------------------------------------------------------
// prep_wqkv2: W{q,k,v}[16][1024][64] -> wt_hi/wt_lo[3072][1024] (operand-major).
// ---------------------------------------------------------------------------
__global__ __launch_bounds__(256) void prep_wqkv2(
    const float* __restrict__ Wq, const float* __restrict__ Wk,
    const float* __restrict__ Wv,
    unsigned short* __restrict__ wh, unsigned short* __restrict__ wl)
{
    const int dt = blockIdx.x;
    const int zh = blockIdx.y;
    const int z = zh >> 4, h = zh & 15;
    const float* src = ((z==0)?Wq:(z==1)?Wk:Wv) + (size_t)h*1024*64;
    __shared__ float Tt[64][68];
    const int t = threadIdx.x;
    const int r = t >> 2, c4 = (t & 3) * 16;
    const float* sp = src + (size_t)(dt*64 + r)*64 + c4;
    float4 v0=*(const float4*)(sp+0), v1=*(const float4*)(sp+4);
    float4 v2=*(const float4*)(sp+8), v3=*(const float4*)(sp+12);
    *(float4*)&Tt[r][c4+ 0]=v0; *(float4*)&Tt[r][c4+ 4]=v1;
    *(float4*)&Tt[r][c4+ 8]=v2; *(float4*)&Tt[r][c4+12]=v3;
    __syncthreads();
    const int er = t >> 2, dk = (t & 3) * 16;
    U16x16 uh, ul;
#pragma unroll
    for (int j=0;j<16;j++){
        float v = Tt[dk+j][er];
        unsigned short hb = f2bf(v);
        uh.us[j] = hb;
        ul.us[j] = f2bf(v - bfbits2f(hb));
    }
    size_t off = (size_t)(z*1024 + h*64 + er)*1024 + dt*64 + dk;
    *(uint4*)(wh+off)   = uh.q[0]; *(uint4*)(wh+off+8) = uh.q[1];
    *(uint4*)(wl+off)   = ul.q[0]; *(uint4*)(wl+off+8) = ul.q[1];
}

// ---------------------------------------------------------------------------
// prep_wo: Wo[1024][1024] -> wot[n][k] bf16 (hi only).
// ---------------------------------------------------------------------------
__global__ __launch_bounds__(256) void prep_wo(
    const float* __restrict__ Wo, unsigned short* __restrict__ wot)
{
    const int kt = blockIdx.x, nt = blockIdx.y;
    __shared__ float Tt[64][68];
    const int t = threadIdx.x;
    const int r = t >> 2, c4 = (t & 3) * 16;
    const float* sp = Wo + (size_t)(kt*64 + r)*1024 + nt*64 + c4;
    float4 v0=*(const float4*)(sp+0), v1=*(const float4*)(sp+4);
    float4 v2=*(const float4*)(sp+8), v3=*(const float4*)(sp+12);
    *(float4*)&Tt[r][c4+ 0]=v0; *(float4*)&Tt[r][c4+ 4]=v1;
    *(float4*)&Tt[r][c4+ 8]=v2; *(float4*)&Tt[r][c4+12]=v3;
    __syncthreads();
    const int er = t >> 2, dk = (t & 3) * 16;
    U16x16 u;
#pragma unroll
    for (int j=0;j<16;j++) u.us[j] = f2bf(Tt[dk+j][er]);
    unsigned short* dst = wot + (size_t)(nt*64 + er)*1024 + kt*64 + dk;
    *(uint4*)(dst)   = u.q[0];
    *(uint4*)(dst+8) = u.q[1];
}

// ---------------------------------------------------------------------------
// gemm_qkv3: C[128x128]/block, 4 waves, 64x64/wave, bf16 16x16x32 MFMA.
// R10 single-buffer loop (32KB LDS, occupancy-friendly): global_load_lds(16B)
// + chunk-XOR swizzle via pre-swizzled source; 0 bank conflicts.
// Split-precision (hi*hi+hi*lo+lo*hi) for q,k (n0<2048).
// Epilogue (R11-verified): two-pass per-wave LDS transpose reusing the staging
// buffers -> contiguous 128B row stores (q/k [t][e]; v transposed [bh][d][t]).
// ---------------------------------------------------------------------------
__global__ __launch_bounds__(256) void gemm_qkv3(
    const unsigned short* __restrict__ xh, const unsigned short* __restrict__ xl,
    const unsigned short* __restrict__ wh, const unsigned short* __restrict__ wl,
    const float* __restrict__ bqv, const float* __restrict__ bkv,
    const float* __restrict__ bvv,
    unsigned short* __restrict__ qhp, unsigned short* __restrict__ qlp,
    unsigned short* __restrict__ khp, unsigned short* __restrict__ klp,
    unsigned short* __restrict__ vtp)
{
    const int m0 = blockIdx.x * 128;
    const int n0 = blockIdx.y * 128;
    const bool precise = (n0 < 2048);
    const int tid = threadIdx.x;
    const int lane = tid & 63, w = tid >> 6;
    const int wr = w >> 1, wc = w & 1;
    const int fla = lane & 15, flb = lane >> 4;

    __shared__ unsigned short Ah[4096];
    __shared__ unsigned short Bh[4096];
    __shared__ unsigned short Al[4096];
    __shared__ unsigned short Bl[4096];

    f32x4 acc[4][4];
#pragma unroll
    for (int i=0;i<4;i++)
#pragma unroll
        for (int j=0;j<4;j++) acc[i][j] = (f32x4){0.f,0.f,0.f,0.f};

    const int srow0 = w*32 + (lane>>2);
    const int srow1 = srow0 + 16;
    const int spc   = lane & 3;
    const size_t ga0 = (size_t)(m0+srow0)*1024 + (size_t)((spc ^ ((srow0>>1)&3))*8);
    const size_t ga1 = (size_t)(m0+srow1)*1024 + (size_t)((spc ^ ((srow1>>1)&3))*8);
    const size_t gb0 = (size_t)(n0+srow0)*1024 + (size_t)((spc ^ ((srow0>>1)&3))*8);
    const size_t gb1 = (size_t)(n0+srow1)*1024 + (size_t)((spc ^ ((srow1>>1)&3))*8);
    const int ldso0 = w*1024;          // shorts
    const int ldso1 = w*1024 + 512;
    const int pchunk = (flb ^ ((fla>>1)&3)) * 8;

    for (int ks = 0; ks < 32; ++ks){
        const size_t k0 = (size_t)ks*32;
        __syncthreads();   // prev chunk's fragment reads complete
        gload_lds16(xh + ga0 + k0, Ah + ldso0);
        gload_lds16(xh + ga1 + k0, Ah + ldso1);
        gload_lds16(wh + gb0 + k0, Bh + ldso0);
        gload_lds16(wh + gb1 + k0, Bh + ldso1);
        if (precise){
            gload_lds16(xl + ga0 + k0, Al + ldso0);
            gload_lds16(xl + ga1 + k0, Al + ldso1);
            gload_lds16(wl + gb0 + k0, Bl + ldso0);
            gload_lds16(wl + gb1 + k0, Bl + ldso1);
        }
        __syncthreads();   // vmcnt(0) drained at barrier

        bf16x8 afh[4], bfh[4];
#pragma unroll
        for (int mf=0; mf<4; ++mf)
            afh[mf] = *(const bf16x8*)&Ah[(wr*64+mf*16+fla)*32 + pchunk];
#pragma unroll
        for (int nf=0; nf<4; ++nf)
            bfh[nf] = *(const bf16x8*)&Bh[(wc*64+nf*16+fla)*32 + pchunk];
        if (precise){
            bf16x8 afl[4], bfl[4];
#pragma unroll
            for (int mf=0; mf<4; ++mf)
                afl[mf] = *(const bf16x8*)&Al[(wr*64+mf*16+fla)*32 + pchunk];
#pragma unroll
            for (int nf=0; nf<4; ++nf)
                bfl[nf] = *(const bf16x8*)&Bl[(wc*64+nf*16+fla)*32 + pchunk];
#pragma unroll
            for (int mf=0; mf<4; ++mf)
#pragma unroll
                for (int nf=0; nf<4; ++nf){
                    acc[mf][nf] = __builtin_amdgcn_mfma_f32_16x16x32_bf16(
                                      afh[mf], bfl[nf], acc[mf][nf], 0, 0, 0);
                    acc[mf][nf] = __builtin_amdgcn_mfma_f32_16x16x32_bf16(
                                      afl[mf], bfh[nf], acc[mf][nf], 0, 0, 0);
                    acc[mf][nf] = __builtin_amdgcn_mfma_f32_16x16x32_bf16(
                                      afh[mf], bfh[nf], acc[mf][nf], 0, 0, 0);
                }
        } else {
#pragma unroll
            for (int mf=0; mf<4; ++mf)
#pragma unroll
                for (int nf=0; nf<4; ++nf)
                    acc[mf][nf] = __builtin_amdgcn_mfma_f32_16x16x32_bf16(
                                      afh[mf], bfh[nf], acc[mf][nf], 0, 0, 0);
        }
    }

    // ---------- epilogue: two-pass per-wave LDS transpose -> 128B row stores
    const int cb  = n0 + wc*64;           // 64-aligned -> single (z,h), e0=0
    const int rem = cb & 1023;
    const int h   = rem >> 6;
    const int mw  = m0 + wr*64;
    const int b   = mw >> 11;
    const int t0  = mw & (T_-1);

    __syncthreads();   // K-loop's final fragment reads done before reuse
#pragma unroll
    for (int pass=0; pass<2; ++pass){
        if ((w>>1) == pass){
            unsigned short* scrH = (w&1) ? Bh : Ah;
            unsigned short* scrL = (w&1) ? Bl : Al;
            if (precise){
                const int z = cb >> 10;
                const float scl = (z==0) ? 8.0f : 1.0f;
                const float* bias = (z==0) ? bqv : bkv;
                unsigned short* oh = (z==0) ? qhp : khp;
                unsigned short* ol = (z==0) ? qlp : klp;
                float biasv[4];
#pragma unroll
                for (int nf=0;nf<4;nf++) biasv[nf] = bias[rem + nf*16 + fla];
                // write: row = t_loc = mf*16+flb*4+ri, col = e = nf*16+fla
#pragma unroll
                for (int mf=0; mf<4; ++mf)
#pragma unroll
                    for (int nf=0; nf<4; ++nf)
#pragma unroll
                        for (int ri=0; ri<4; ++ri){
                            const int row = mf*16 + flb*4 + ri;
                            const int col = nf*16 + fla;
                            const int a = row*64 + (((col>>3) ^ (row&7))<<3) + (col&7);
                            const float val = (acc[mf][nf][ri] + biasv[nf]) * scl;
                            const unsigned short hb = f2bf(val);
                            scrH[a] = hb;
                            scrL[a] = f2bf(val - bfbits2f(hb));
                        }
                const size_t rowbase = ((size_t)(b*H_ + h)*T_ + t0 + lane)*HD_;
#pragma unroll
                for (int c=0;c<8;c++){
                    const int pc = (c ^ (lane&7))<<3;
                    *(uint4*)(oh + rowbase + c*8) = *(const uint4*)&scrH[lane*64 + pc];
                    *(uint4*)(ol + rowbase + c*8) = *(const uint4*)&scrL[lane*64 + pc];
                }
            } else {
                float biasv[4];
#pragma unroll
                for (int nf=0;nf<4;nf++) biasv[nf] = bvv[rem + nf*16 + fla];
                // write transposed: row = e = nf*16+fla, col = t_loc
#pragma unroll
                for (int mf=0; mf<4; ++mf)
#pragma unroll
                    for (int nf=0; nf<4; ++nf)
#pragma unroll
                        for (int ri=0; ri<4; ++ri){
                            const int row = nf*16 + fla;
                            const int col = mf*16 + flb*4 + ri;
                            const int a = row*64 + (((col>>3) ^ (row&7))<<3) + (col&7);
                            scrH[a] = f2bf(acc[mf][nf][ri] + biasv[nf]);
                        }
                const size_t rowbase = ((size_t)((b*H_ + h)*HD_ + lane))*T_ + t0;
#pragma unroll
                for (int c=0;c<8;c++){
                    const int pc = (c ^ (lane&7))<<3;
                    *(uint4*)(vtp + rowbase + c*8) = *(const uint4*)&scrH[lane*64 + pc];
                }
            }
        }
        __syncthreads();
    }
}

// ---------------------------------------------------------------------------
// gemm_o: out = att(bf16) @ wot(bf16) + bo. Single-buffer gload_lds + swizzle
// (16KB LDS; same proven scheme as gemm_qkv3 hi path).
// ---------------------------------------------------------------------------
__global__ __launch_bounds__(256) void gemm_o(
    const unsigned short* __restrict__ attb, const unsigned short* __restrict__ wot,
    const float* __restrict__ bo, float* __restrict__ out)
{
    const int m0 = blockIdx.x * 128;
    const int n0 = blockIdx.y * 128;
    const int tid = threadIdx.x;
    const int lane = tid & 63, w = tid >> 6;
    const int wr = w >> 1, wc = w & 1;
    const int fla = lane & 15, flb = lane >> 4;

    __shared__ unsigned short As[4096];
    __shared__ unsigned short Bs[4096];

    f32x4 acc[4][4];
#pragma unroll
    for (int i=0;i<4;i++)
#pragma unroll
        for (int j=0;j<4;j++) acc[i][j] = (f32x4){0.f,0.f,0.f,0.f};

    const int srow0 = w*32 + (lane>>2);
    const int srow1 = srow0 + 16;
    const int spc   = lane & 3;
    const size_t ga0 = (size_t)(m0+srow0)*1024 + (size_t)((spc ^ ((srow0>>1)&3))*8);
    const size_t ga1 = (size_t)(m0+srow1)*1024 + (size_t)((spc ^ ((srow1>>1)&3))*8);
    const size_t gb0 = (size_t)(n0+srow0)*1024 + (size_t)((spc ^ ((srow0>>1)&3))*8);
    const size_t gb1 = (size_t)(n0+srow1)*1024 + (size_t)((spc ^ ((srow1>>1)&3))*8);
    const int ldso0 = w*1024;
    const int ldso1 = w*1024 + 512;
    const int pchunk = (flb ^ ((fla>>1)&3)) * 8;

    for (int ks = 0; ks < 32; ++ks){
        const size_t k0 = (size_t)ks*32;
        __syncthreads();
        gload_lds16(attb + ga0 + k0, As + ldso0);
        gload_lds16(attb + ga1 + k0, As + ldso1);
        gload_lds16(wot  + gb0 + k0, Bs + ldso0);
        gload_lds16(wot  + gb1 + k0, Bs + ldso1);
        __syncthreads();

        bf16x8 af[4], bfr[4];
#pragma unroll
        for (int mf=0; mf<4; ++mf)
            af[mf] = *(const bf16x8*)&As[(wr*64+mf*16+fla)*32 + pchunk];
#pragma unroll
        for (int nf=0; nf<4; ++nf)
            bfr[nf] = *(const bf16x8*)&Bs[(wc*64+nf*16+fla)*32 + pchunk];
#pragma unroll
        for (int mf=0; mf<4; ++mf)
#pragma unroll
            for (int nf=0; nf<4; ++nf)
                acc[mf][nf] = __builtin_amdgcn_mfma_f32_16x16x32_bf16(
                                  af[mf], bfr[nf], acc[mf][nf], 0, 0, 0);
    }

#pragma unroll
    for (int nf=0; nf<4; ++nf){
        const int n = n0 + wc*64 + nf*16 + fla;
        const float bias = bo[n];
#pragma unroll
        for (int mf=0; mf<4; ++mf){
#pragma unroll
            for (int ri=0; ri<4; ++ri){
                const int m = m0 + wr*64 + mf*16 + flb*4 + ri;
                out[(size_t)m*D_ + n] = acc[mf][nf][ri] + bias;
            }
        }
    }
}

// ---------------------------------------------------------------------------
// MFMA flash attention. (unchanged from round 10)
// ---------------------------------------------------------------------------
__global__ __launch_bounds__(256) void attn_mfma(
    const unsigned short* __restrict__ qhp, const unsigned short* __restrict__ qlp,
    const unsigned short* __restrict__ khp, const unsigned short* __restrict__ klp,
    const unsigned short* __restrict__ vtp, unsigned short* __restrict__ attb,
    const int* __restrict__ maskp)
{
    const int bid = blockIdx.x;
    const int qb  = 31 - (bid >> 6);   // big blocks first
    const int bh  = bid & 63;
    const int b   = bh >> 4, h = bh & 15;
    const int tid = threadIdx.x;
    const int lane = tid & 63, w = tid >> 6;
    const int l16 = lane & 15, h16 = lane >> 4;
    const int domask = maskp[0];

    __shared__ unsigned short KhS[64][72];
    __shared__ unsigned short KlS[64][72];
    __shared__ unsigned short VtS[64][72];   // [d][key]
    __shared__ unsigned short PsS[64][72];   // wave-private rows

    const int qrow = qb*64 + w*16 + l16;
    const size_t qoff = ((size_t)bh*T_ + qrow)*HD_ + 8*h16;
    const bf16x8 qh0 = *(const bf16x8*)(qhp + qoff);
    const bf16x8 qh1 = *(const bf16x8*)(qhp + qoff + 32);
    const bf16x8 ql0 = *(const bf16x8*)(qlp + qoff);
    const bf16x8 ql1 = *(const bf16x8*)(qlp + qoff + 32);

    f32x4 accO[4];
#pragma unroll
    for (int j=0;j<4;j++) accO[j] = (f32x4){0.f,0.f,0.f,0.f};
    float m_run[4], l_run[4];
#pragma unroll
    for (int i=0;i<4;i++){ m_run[i] = -INFINITY; l_run[i] = 0.f; }

    const int r   = tid >> 2;         // staging row 0..63
    const int c16 = (tid & 3) * 16;   // staging col base
    const size_t kbase = (size_t)bh*T_*HD_;
    const size_t vbase = (size_t)bh*HD_*T_;

    const int kv_end = domask ? qb : 31;
    for (int kv = 0; kv <= kv_end; ++kv){
        const unsigned short* ksrc = khp + kbase + (size_t)(kv*64+r)*HD_ + c16;
        uint4 a0 = *(const uint4*)(ksrc);
        uint4 a1 = *(const uint4*)(ksrc+8);
        const unsigned short* lsrc = klp + kbase + (size_t)(kv*64+r)*HD_ + c16;
        uint4 a2 = *(const uint4*)(lsrc);
        uint4 a3 = *(const uint4*)(lsrc+8);
        const unsigned short* vsrc = vtp + vbase + (size_t)r*T_ + kv*64 + c16;
        uint4 a4 = *(const uint4*)(vsrc);
        uint4 a5 = *(const uint4*)(vsrc+8);
        __syncthreads();   // prev tile reads done
        *(uint4*)&KhS[r][c16] = a0; *(uint4*)&KhS[r][c16+8] = a1;
        *(uint4*)&KlS[r][c16] = a2; *(uint4*)&KlS[r][c16+8] = a3;
        *(uint4*)&VtS[r][c16] = a4; *(uint4*)&VtS[r][c16+8] = a5;
        __syncthreads();

        // S = Q K^T  (split precision, small terms first)
        f32x4 s[4];
#pragma unroll
        for (int j=0;j<4;j++){
            const bf16x8 kh0 = *(const bf16x8*)&KhS[j*16+l16][8*h16];
            const bf16x8 kh1 = *(const bf16x8*)&KhS[j*16+l16][32+8*h16];
            const bf16x8 kl0 = *(const bf16x8*)&KlS[j*16+l16][8*h16];
            const bf16x8 kl1 = *(const bf16x8*)&KlS[j*16+l16][32+8*h16];
            f32x4 a = (f32x4){0.f,0.f,0.f,0.f};
            a = __builtin_amdgcn_mfma_f32_16x16x32_bf16(qh0, kl0, a, 0,0,0);
            a = __builtin_amdgcn_mfma_f32_16x16x32_bf16(ql0, kh0, a, 0,0,0);
            a = __builtin_amdgcn_mfma_f32_16x16x32_bf16(qh1, kl1, a, 0,0,0);
            a = __builtin_amdgcn_mfma_f32_16x16x32_bf16(ql1, kh1, a, 0,0,0);
            a = __builtin_amdgcn_mfma_f32_16x16x32_bf16(qh0, kh0, a, 0,0,0);
            a = __builtin_amdgcn_mfma_f32_16x16x32_bf16(qh1, kh1, a, 0,0,0);
            s[j] = a;
        }
        if (domask && kv == qb){
#pragma unroll
            for (int j=0;j<4;j++)
#pragma unroll
                for (int reg=0;reg<4;reg++)
                    if (j*16+l16 > w*16 + h16*4 + reg) s[j][reg] = -INFINITY;
        }

        // online softmax; rows = w*16 + h16*4 + reg
#pragma unroll
        for (int reg=0; reg<4; ++reg){
            float mloc = fmaxf(fmaxf(s[0][reg],s[1][reg]), fmaxf(s[2][reg],s[3][reg]));
            mloc = fmaxf(mloc, __shfl_xor(mloc,1));
            mloc = fmaxf(mloc, __shfl_xor(mloc,2));
            mloc = fmaxf(mloc, __shfl_xor(mloc,4));
            mloc = fmaxf(mloc, __shfl_xor(mloc,8));
            float mnew = fmaxf(m_run[reg], mloc);
            float scl  = __expf(m_run[reg] - mnew);   // exp(-inf)=0 first tile
            m_run[reg] = mnew;
            float p0 = __expf(s[0][reg]-mnew);
            float p1 = __expf(s[1][reg]-mnew);
            float p2 = __expf(s[2][reg]-mnew);
            float p3 = __expf(s[3][reg]-mnew);
            float rs = p0+p1+p2+p3;
            rs += __shfl_xor(rs,1); rs += __shfl_xor(rs,2);
            rs += __shfl_xor(rs,4); rs += __shfl_xor(rs,8);
            l_run[reg] = l_run[reg]*scl + rs;
            accO[0][reg] *= scl; accO[1][reg] *= scl;
            accO[2][reg] *= scl; accO[3][reg] *= scl;
            const int prow = w*16 + h16*4 + reg;
            PsS[prow][ 0+l16] = f2bf(p0);
            PsS[prow][16+l16] = f2bf(p1);
            PsS[prow][32+l16] = f2bf(p2);
            PsS[prow][48+l16] = f2bf(p3);
        }

        // O += P V  (PsS rows wave-private)
#pragma unroll
        for (int c=0;c<2;c++){
            const bf16x8 pa = *(const bf16x8*)&PsS[w*16+l16][c*32+8*h16];
#pragma unroll
            for (int j=0;j<4;j++){
                const bf16x8 vb_ = *(const bf16x8*)&VtS[j*16+l16][c*32+8*h16];
                accO[j] = __builtin_amdgcn_mfma_f32_16x16x32_bf16(pa, vb_, accO[j], 0,0,0);
            }
        }
    }

#pragma unroll
    for (int reg=0;reg<4;reg++){
        const float inv = 1.0f / l_run[reg];
        const int t = qb*64 + w*16 + h16*4 + reg;
#pragma unroll
        for (int j=0;j<4;j++){
            attb[((size_t)b*T_ + t)*D_ + h*HD_ + j*16 + l16] =
                f2bf(accO[j][reg]*inv);
        }
    }
}

extern "C" void kernel_launch(void* const* d_in, const int* in_sizes, int n_in,
                              void* d_out, int out_size, void* d_ws, size_t ws_size,
                              hipStream_t stream)
{
    const float* x  = (const float*)d_in[0];
    const float* Wq = (const float*)d_in[1];
    const float* bq = (const float*)d_in[2];
    const float* Wk = (const float*)d_in[3];
    const float* bk = (const float*)d_in[4];
    const float* Wv = (const float*)d_in[5];
    const float* bv = (const float*)d_in[6];
    const float* Wo = (const float*)d_in[7];
    const float* bo = (const float*)d_in[8];
    const int* mask = (const int*)d_in[9];
    float* out = (float*)d_out;

    // workspace (126 MiB): all bf16
    unsigned short* qhp = (unsigned short*)d_ws;                 // 16 MiB
    unsigned short* qlp = qhp + (size_t)8*1024*1024;             // 16 MiB
    unsigned short* khp = qlp + (size_t)8*1024*1024;             // 16 MiB
    unsigned short* klp = khp + (size_t)8*1024*1024;             // 16 MiB
    unsigned short* vtp = klp + (size_t)8*1024*1024;             // 16 MiB [bh][d][t]
    unsigned short* xh  = vtp + (size_t)8*1024*1024;             // 16 MiB
    unsigned short* xl  = xh  + (size_t)8*1024*1024;             // 16 MiB
    unsigned short* wh  = xl  + (size_t)8*1024*1024;             // 6 MiB
    unsigned short* wl  = wh  + (size_t)3*1024*1024;             // 6 MiB
    unsigned short* wot = wl  + (size_t)3*1024*1024;             // 2 MiB
    unsigned short* attb = xh;   // alias: xh dead after gemm_qkv3

    prep_x2   <<<2048, 256, 0, stream>>>(x, xh, xl);
    prep_wqkv2<<<dim3(16,48), 256, 0, stream>>>(Wq, Wk, Wv, wh, wl);
    prep_wo   <<<dim3(16,16), 256, 0, stream>>>(Wo, wot);
    gemm_qkv3 <<<dim3(64,24), 256, 0, stream>>>(xh, xl, wh, wl, bq, bk, bv,
                                                qhp, qlp, khp, klp, vtp);
    attn_mfma <<<2048, 256, 0, stream>>>(qhp, qlp, khp, klp, vtp, attb, mask);
    gemm_o    <<<dim3(64,8), 256, 0, stream>>>(attb, wot, bo, out);
}

// Round 13
// 313.842 us; speedup vs baseline: 1.3373x; 1.3373x over previous
//
#include <hip/hip_runtime.h>
#include <hip/hip_bf16.h>
#include <math.h>

#define B_  4
#define T_  2048
#define D_  1024
#define H_  16
#define HD_ 64
#define M_  8192   // B_*T_

typedef __attribute__((ext_vector_type(8))) short bf16x8;
typedef __attribute__((ext_vector_type(4))) float f32x4;

static __device__ __forceinline__ unsigned short f2bf(float f){
    unsigned int u = __float_as_uint(f);
    unsigned int r = u + 0x7FFFu + ((u >> 16) & 1u);   // RNE
    return (unsigned short)(r >> 16);
}
static __device__ __forceinline__ float bfbits2f(unsigned short s){
    return __uint_as_float(((unsigned int)s) << 16);
}
static __device__ __forceinline__ void gload_lds16(const void* g, void* l){
    __builtin_amdgcn_global_load_lds(
        (const __attribute__((address_space(1))) unsigned int*)g,
        (__attribute__((address_space(3))) unsigned int*)l, 16, 0, 0);
}

union U16x16 { unsigned short us[16]; uint4 q[2]; };
union U16x4  { unsigned short us[4];  uint2 q;    };

// ---------------------------------------------------------------------------
// prep_x2: x fp32 -> xh (bf16 hi) + xl (bf16 residual). 16 el/thread.
// ---------------------------------------------------------------------------
__global__ __launch_bounds__(256) void prep_x2(
    const float* __restrict__ x,
    unsigned short* __restrict__ xh, unsigned short* __restrict__ xl)
{
    const size_t i = ((size_t)blockIdx.x*256 + threadIdx.x)*16;
    U16x16 uh, ul;
#pragma unroll
    for (int j=0;j<16;j+=4){
        float4 f = *(const float4*)(x+i+j);
        float v[4] = {f.x,f.y,f.z,f.w};
#pragma unroll
        for (int k=0;k<4;k++){
            unsigned short hb = f2bf(v[k]);
            uh.us[j+k] = hb;
            ul.us[j+k] = f2bf(v[k] - bfbits2f(hb));
        }
    }
    *(uint4*)(xh+i)   = uh.q[0]; *(uint4*)(xh+i+8) = uh.q[1];
    *(uint4*)(xl+i)   = ul.q[0]; *(uint4*)(xl+i+8) = ul.q[1];
}

// ---------------------------------------------------------------------------
// prep_wqkv2: W{q,k,v}[16][1024][64] -> wt_hi/wt_lo[3072][1024] (operand-major).
// ---------------------------------------------------------------------------
__global__ __launch_bounds__(256) void prep_wqkv2(
    const float* __restrict__ Wq, const float* __restrict__ Wk,
    const float* __restrict__ Wv,
    unsigned short* __restrict__ wh, unsigned short* __restrict__ wl)
{
    const int dt = blockIdx.x;
    const int zh = blockIdx.y;
    const int z = zh >> 4, h = zh & 15;
    const float* src = ((z==0)?Wq:(z==1)?Wk:Wv) + (size_t)h*1024*64;
    __shared__ float Tt[64][68];
    const int t = threadIdx.x;
    const int r = t >> 2, c4 = (t & 3) * 16;
    const float* sp = src + (size_t)(dt*64 + r)*64 + c4;
    float4 v0=*(const float4*)(sp+0), v1=*(const float4*)(sp+4);
    float4 v2=*(const float4*)(sp+8), v3=*(const float4*)(sp+12);
    *(float4*)&Tt[r][c4+ 0]=v0; *(float4*)&Tt[r][c4+ 4]=v1;
    *(float4*)&Tt[r][c4+ 8]=v2; *(float4*)&Tt[r][c4+12]=v3;
    __syncthreads();
    const int er = t >> 2, dk = (t & 3) * 16;
    U16x16 uh, ul;
#pragma unroll
    for (int j=0;j<16;j++){
        float v = Tt[dk+j][er];
        unsigned short hb = f2bf(v);
        uh.us[j] = hb;
        ul.us[j] = f2bf(v - bfbits2f(hb));
    }
    size_t off = (size_t)(z*1024 + h*64 + er)*1024 + dt*64 + dk;
    *(uint4*)(wh+off)   = uh.q[0]; *(uint4*)(wh+off+8) = uh.q[1];
    *(uint4*)(wl+off)   = ul.q[0]; *(uint4*)(wl+off+8) = ul.q[1];
}

// ---------------------------------------------------------------------------
// prep_wo: Wo[1024][1024] -> wot[n][k] bf16 (hi only).
// ---------------------------------------------------------------------------
__global__ __launch_bounds__(256) void prep_wo(
    const float* __restrict__ Wo, unsigned short* __restrict__ wot)
{
    const int kt = blockIdx.x, nt = blockIdx.y;
    __shared__ float Tt[64][68];
    const int t = threadIdx.x;
    const int r = t >> 2, c4 = (t & 3) * 16;
    const float* sp = Wo + (size_t)(kt*64 + r)*1024 + nt*64 + c4;
    float4 v0=*(const float4*)(sp+0), v1=*(const float4*)(sp+4);
    float4 v2=*(const float4*)(sp+8), v3=*(const float4*)(sp+12);
    *(float4*)&Tt[r][c4+ 0]=v0; *(float4*)&Tt[r][c4+ 4]=v1;
    *(float4*)&Tt[r][c4+ 8]=v2; *(float4*)&Tt[r][c4+12]=v3;
    __syncthreads();
    const int er = t >> 2, dk = (t & 3) * 16;
    U16x16 u;
#pragma unroll
    for (int j=0;j<16;j++) u.us[j] = f2bf(Tt[dk+j][er]);
    unsigned short* dst = wot + (size_t)(nt*64 + er)*1024 + kt*64 + dk;
    *(uint4*)(dst)   = u.q[0];
    *(uint4*)(dst+8) = u.q[1];
}

// ---------------------------------------------------------------------------
// gemm_qkv3: EXACT R10 version (measured 154us, VGPR 120, MfmaUtil 34.5%).
// C[128x128]/block, 4 waves, 64x64/wave, bf16 16x16x32 MFMA. Single-buffer
// global_load_lds(16B) + chunk-XOR swizzle via pre-swizzled source (0 bank
// conflicts). Split-precision (hi*hi+hi*lo+lo*hi) for q,k (n0<2048).
// v: single product, output bf16 TRANSPOSED [bh][d][t] via uint2 stores.
// ---------------------------------------------------------------------------
__global__ __launch_bounds__(256) void gemm_qkv3(
    const unsigned short* __restrict__ xh, const unsigned short* __restrict__ xl,
    const unsigned short* __restrict__ wh, const unsigned short* __restrict__ wl,
    const float* __restrict__ bqv, const float* __restrict__ bkv,
    const float* __restrict__ bvv,
    unsigned short* __restrict__ qhp, unsigned short* __restrict__ qlp,
    unsigned short* __restrict__ khp, unsigned short* __restrict__ klp,
    unsigned short* __restrict__ vtp)
{
    const int m0 = blockIdx.x * 128;
    const int n0 = blockIdx.y * 128;
    const bool precise = (n0 < 2048);
    const int tid = threadIdx.x;
    const int lane = tid & 63, w = tid >> 6;
    const int wr = w >> 1, wc = w & 1;
    const int fla = lane & 15, flb = lane >> 4;

    __shared__ unsigned short Ah[128*32];
    __shared__ unsigned short Bh[128*32];
    __shared__ unsigned short Al[128*32];
    __shared__ unsigned short Bl[128*32];

    f32x4 acc[4][4];
#pragma unroll
    for (int i=0;i<4;i++)
#pragma unroll
        for (int j=0;j<4;j++) acc[i][j] = (f32x4){0.f,0.f,0.f,0.f};

    const int srow0 = w*32 + (lane>>2);
    const int srow1 = srow0 + 16;
    const int spc   = lane & 3;
    const size_t ga0 = (size_t)(m0+srow0)*1024 + (size_t)((spc ^ ((srow0>>1)&3))*8);
    const size_t ga1 = (size_t)(m0+srow1)*1024 + (size_t)((spc ^ ((srow1>>1)&3))*8);
    const size_t gb0 = (size_t)(n0+srow0)*1024 + (size_t)((spc ^ ((srow0>>1)&3))*8);
    const size_t gb1 = (size_t)(n0+srow1)*1024 + (size_t)((spc ^ ((srow1>>1)&3))*8);
    const int ldso0 = w*1024;          // shorts
    const int ldso1 = w*1024 + 512;
    const int pchunk = (flb ^ ((fla>>1)&3)) * 8;

    for (int ks = 0; ks < 32; ++ks){
        const size_t k0 = (size_t)ks*32;
        __syncthreads();   // prev chunk's fragment reads complete
        gload_lds16(xh + ga0 + k0, Ah + ldso0);
        gload_lds16(xh + ga1 + k0, Ah + ldso1);
        gload_lds16(wh + gb0 + k0, Bh + ldso0);
        gload_lds16(wh + gb1 + k0, Bh + ldso1);
        if (precise){
            gload_lds16(xl + ga0 + k0, Al + ldso0);
            gload_lds16(xl + ga1 + k0, Al + ldso1);
            gload_lds16(wl + gb0 + k0, Bl + ldso0);
            gload_lds16(wl + gb1 + k0, Bl + ldso1);
        }
        __syncthreads();   // vmcnt(0) drained before barrier (compiler)

        bf16x8 afh[4], bfh[4];
#pragma unroll
        for (int mf=0; mf<4; ++mf)
            afh[mf] = *(const bf16x8*)&Ah[(wr*64+mf*16+fla)*32 + pchunk];
#pragma unroll
        for (int nf=0; nf<4; ++nf)
            bfh[nf] = *(const bf16x8*)&Bh[(wc*64+nf*16+fla)*32 + pchunk];
        if (precise){
            bf16x8 afl[4], bfl[4];
#pragma unroll
            for (int mf=0; mf<4; ++mf)
                afl[mf] = *(const bf16x8*)&Al[(wr*64+mf*16+fla)*32 + pchunk];
#pragma unroll
            for (int nf=0; nf<4; ++nf)
                bfl[nf] = *(const bf16x8*)&Bl[(wc*64+nf*16+fla)*32 + pchunk];
#pragma unroll
            for (int mf=0; mf<4; ++mf)
#pragma unroll
                for (int nf=0; nf<4; ++nf){
                    acc[mf][nf] = __builtin_amdgcn_mfma_f32_16x16x32_bf16(
                                      afh[mf], bfl[nf], acc[mf][nf], 0, 0, 0);
                    acc[mf][nf] = __builtin_amdgcn_mfma_f32_16x16x32_bf16(
                                      afl[mf], bfh[nf], acc[mf][nf], 0, 0, 0);
                    acc[mf][nf] = __builtin_amdgcn_mfma_f32_16x16x32_bf16(
                                      afh[mf], bfh[nf], acc[mf][nf], 0, 0, 0);
                }
        } else {
#pragma unroll
            for (int mf=0; mf<4; ++mf)
#pragma unroll
                for (int nf=0; nf<4; ++nf)
                    acc[mf][nf] = __builtin_amdgcn_mfma_f32_16x16x32_bf16(
                                      afh[mf], bfh[nf], acc[mf][nf], 0, 0, 0);
        }
    }

    if (precise){
#pragma unroll
        for (int nf=0; nf<4; ++nf){
            const int c = n0 + wc*64 + nf*16 + fla;
            const int z = c >> 10, rem = c & 1023;
            const int h = rem >> 6, e = rem & 63;
            const float bias = ((z==0)?bqv:bkv)[rem];
            const float scl  = (z==0) ? 8.0f : 1.0f;
            unsigned short* oh = (z==0)?qhp:khp;
            unsigned short* ol = (z==0)?qlp:klp;
#pragma unroll
            for (int mf=0; mf<4; ++mf){
#pragma unroll
                for (int ri=0; ri<4; ++ri){
                    const int m = m0 + wr*64 + mf*16 + flb*4 + ri;
                    const int b = m >> 11, t = m & (T_-1);
                    const float val = (acc[mf][nf][ri] + bias) * scl;
                    const unsigned short hb = f2bf(val);
                    const size_t idx = ((size_t)(b*H_ + h)*T_ + t)*HD_ + e;
                    oh[idx] = hb;
                    ol[idx] = f2bf(val - bfbits2f(hb));
                }
            }
        }
    } else {
#pragma unroll
        for (int nf=0; nf<4; ++nf){
            const int c = n0 + wc*64 + nf*16 + fla;
            const int rem = c & 1023;
            const int h = rem >> 6, e = rem & 63;
            const float bias = bvv[rem];
#pragma unroll
            for (int mf=0; mf<4; ++mf){
                const int m = m0 + wr*64 + mf*16 + flb*4;   // 4 consecutive t
                const int b = m >> 11, t = m & (T_-1);
                U16x4 u;
#pragma unroll
                for (int ri=0; ri<4; ++ri)
                    u.us[ri] = f2bf(acc[mf][nf][ri] + bias);
                *(uint2*)(vtp + ((size_t)(b*H_ + h)*HD_ + e)*T_ + t) = u.q;
            }
        }
    }
}

// ---------------------------------------------------------------------------
// gemm_o: out = att(bf16) @ wot(bf16) + bo. Single-buffer gload_lds + swizzle
// (16KB LDS; validated in R12).
// ---------------------------------------------------------------------------
__global__ __launch_bounds__(256) void gemm_o(
    const unsigned short* __restrict__ attb, const unsigned short* __restrict__ wot,
    const float* __restrict__ bo, float* __restrict__ out)
{
    const int m0 = blockIdx.x * 128;
    const int n0 = blockIdx.y * 128;
    const int tid = threadIdx.x;
    const int lane = tid & 63, w = tid >> 6;
    const int wr = w >> 1, wc = w & 1;
    const int fla = lane & 15, flb = lane >> 4;

    __shared__ unsigned short As[4096];
    __shared__ unsigned short Bs[4096];

    f32x4 acc[4][4];
#pragma unroll
    for (int i=0;i<4;i++)
#pragma unroll
        for (int j=0;j<4;j++) acc[i][j] = (f32x4){0.f,0.f,0.f,0.f};

    const int srow0 = w*32 + (lane>>2);
    const int srow1 = srow0 + 16;
    const int spc   = lane & 3;
    const size_t ga0 = (size_t)(m0+srow0)*1024 + (size_t)((spc ^ ((srow0>>1)&3))*8);
    const size_t ga1 = (size_t)(m0+srow1)*1024 + (size_t)((spc ^ ((srow1>>1)&3))*8);
    const size_t gb0 = (size_t)(n0+srow0)*1024 + (size_t)((spc ^ ((srow0>>1)&3))*8);
    const size_t gb1 = (size_t)(n0+srow1)*1024 + (size_t)((spc ^ ((srow1>>1)&3))*8);
    const int ldso0 = w*1024;
    const int ldso1 = w*1024 + 512;
    const int pchunk = (flb ^ ((fla>>1)&3)) * 8;

    for (int ks = 0; ks < 32; ++ks){
        const size_t k0 = (size_t)ks*32;
        __syncthreads();
        gload_lds16(attb + ga0 + k0, As + ldso0);
        gload_lds16(attb + ga1 + k0, As + ldso1);
        gload_lds16(wot  + gb0 + k0, Bs + ldso0);
        gload_lds16(wot  + gb1 + k0, Bs + ldso1);
        __syncthreads();

        bf16x8 af[4], bfr[4];
#pragma unroll
        for (int mf=0; mf<4; ++mf)
            af[mf] = *(const bf16x8*)&As[(wr*64+mf*16+fla)*32 + pchunk];
#pragma unroll
        for (int nf=0; nf<4; ++nf)
            bfr[nf] = *(const bf16x8*)&Bs[(wc*64+nf*16+fla)*32 + pchunk];
#pragma unroll
        for (int mf=0; mf<4; ++mf)
#pragma unroll
            for (int nf=0; nf<4; ++nf)
                acc[mf][nf] = __builtin_amdgcn_mfma_f32_16x16x32_bf16(
                                  af[mf], bfr[nf], acc[mf][nf], 0, 0, 0);
    }

#pragma unroll
    for (int nf=0; nf<4; ++nf){
        const int n = n0 + wc*64 + nf*16 + fla;
        const float bias = bo[n];
#pragma unroll
        for (int mf=0; mf<4; ++mf){
#pragma unroll
            for (int ri=0; ri<4; ++ri){
                const int m = m0 + wr*64 + mf*16 + flb*4 + ri;
                out[(size_t)m*D_ + n] = acc[mf][nf][ri] + bias;
            }
        }
    }
}

// ---------------------------------------------------------------------------
// MFMA flash attention. (unchanged from round 10)
// ---------------------------------------------------------------------------
__global__ __launch_bounds__(256) void attn_mfma(
    const unsigned short* __restrict__ qhp, const unsigned short* __restrict__ qlp,
    const unsigned short* __restrict__ khp, const unsigned short* __restrict__ klp,
    const unsigned short* __restrict__ vtp, unsigned short* __restrict__ attb,
    const int* __restrict__ maskp)
{
    const int bid = blockIdx.x;
    const int qb  = 31 - (bid >> 6);   // big blocks first
    const int bh  = bid & 63;
    const int b   = bh >> 4, h = bh & 15;
    const int tid = threadIdx.x;
    const int lane = tid & 63, w = tid >> 6;
    const int l16 = lane & 15, h16 = lane >> 4;
    const int domask = maskp[0];

    __shared__ unsigned short KhS[64][72];
    __shared__ unsigned short KlS[64][72];
    __shared__ unsigned short VtS[64][72];   // [d][key]
    __shared__ unsigned short PsS[64][72];   // wave-private rows

    const int qrow = qb*64 + w*16 + l16;
    const size_t qoff = ((size_t)bh*T_ + qrow)*HD_ + 8*h16;
    const bf16x8 qh0 = *(const bf16x8*)(qhp + qoff);
    const bf16x8 qh1 = *(const bf16x8*)(qhp + qoff + 32);
    const bf16x8 ql0 = *(const bf16x8*)(qlp + qoff);
    const bf16x8 ql1 = *(const bf16x8*)(qlp + qoff + 32);

    f32x4 accO[4];
#pragma unroll
    for (int j=0;j<4;j++) accO[j] = (f32x4){0.f,0.f,0.f,0.f};
    float m_run[4], l_run[4];
#pragma unroll
    for (int i=0;i<4;i++){ m_run[i] = -INFINITY; l_run[i] = 0.f; }

    const int r   = tid >> 2;         // staging row 0..63
    const int c16 = (tid & 3) * 16;   // staging col base
    const size_t kbase = (size_t)bh*T_*HD_;
    const size_t vbase = (size_t)bh*HD_*T_;

    const int kv_end = domask ? qb : 31;
    for (int kv = 0; kv <= kv_end; ++kv){
        const unsigned short* ksrc = khp + kbase + (size_t)(kv*64+r)*HD_ + c16;
        uint4 a0 = *(const uint4*)(ksrc);
        uint4 a1 = *(const uint4*)(ksrc+8);
        const unsigned short* lsrc = klp + kbase + (size_t)(kv*64+r)*HD_ + c16;
        uint4 a2 = *(const uint4*)(lsrc);
        uint4 a3 = *(const uint4*)(lsrc+8);
        const unsigned short* vsrc = vtp + vbase + (size_t)r*T_ + kv*64 + c16;
        uint4 a4 = *(const uint4*)(vsrc);
        uint4 a5 = *(const uint4*)(vsrc+8);
        __syncthreads();   // prev tile reads done
        *(uint4*)&KhS[r][c16] = a0; *(uint4*)&KhS[r][c16+8] = a1;
        *(uint4*)&KlS[r][c16] = a2; *(uint4*)&KlS[r][c16+8] = a3;
        *(uint4*)&VtS[r][c16] = a4; *(uint4*)&VtS[r][c16+8] = a5;
        __syncthreads();

        // S = Q K^T  (split precision, small terms first)
        f32x4 s[4];
#pragma unroll
        for (int j=0;j<4;j++){
            const bf16x8 kh0 = *(const bf16x8*)&KhS[j*16+l16][8*h16];
            const bf16x8 kh1 = *(const bf16x8*)&KhS[j*16+l16][32+8*h16];
            const bf16x8 kl0 = *(const bf16x8*)&KlS[j*16+l16][8*h16];
            const bf16x8 kl1 = *(const bf16x8*)&KlS[j*16+l16][32+8*h16];
            f32x4 a = (f32x4){0.f,0.f,0.f,0.f};
            a = __builtin_amdgcn_mfma_f32_16x16x32_bf16(qh0, kl0, a, 0,0,0);
            a = __builtin_amdgcn_mfma_f32_16x16x32_bf16(ql0, kh0, a, 0,0,0);
            a = __builtin_amdgcn_mfma_f32_16x16x32_bf16(qh1, kl1, a, 0,0,0);
            a = __builtin_amdgcn_mfma_f32_16x16x32_bf16(ql1, kh1, a, 0,0,0);
            a = __builtin_amdgcn_mfma_f32_16x16x32_bf16(qh0, kh0, a, 0,0,0);
            a = __builtin_amdgcn_mfma_f32_16x16x32_bf16(qh1, kh1, a, 0,0,0);
            s[j] = a;
        }
        if (domask && kv == qb){
#pragma unroll
            for (int j=0;j<4;j++)
#pragma unroll
                for (int reg=0;reg<4;reg++)
                    if (j*16+l16 > w*16 + h16*4 + reg) s[j][reg] = -INFINITY;
        }

        // online softmax; rows = w*16 + h16*4 + reg
#pragma unroll
        for (int reg=0; reg<4; ++reg){
            float mloc = fmaxf(fmaxf(s[0][reg],s[1][reg]), fmaxf(s[2][reg],s[3][reg]));
            mloc = fmaxf(mloc, __shfl_xor(mloc,1));
            mloc = fmaxf(mloc, __shfl_xor(mloc,2));
            mloc = fmaxf(mloc, __shfl_xor(mloc,4));
            mloc = fmaxf(mloc, __shfl_xor(mloc,8));
            float mnew = fmaxf(m_run[reg], mloc);
            float scl  = __expf(m_run[reg] - mnew);   // exp(-inf)=0 first tile
            m_run[reg] = mnew;
            float p0 = __expf(s[0][reg]-mnew);
            float p1 = __expf(s[1][reg]-mnew);
            float p2 = __expf(s[2][reg]-mnew);
            float p3 = __expf(s[3][reg]-mnew);
            float rs = p0+p1+p2+p3;
            rs += __shfl_xor(rs,1); rs += __shfl_xor(rs,2);
            rs += __shfl_xor(rs,4); rs += __shfl_xor(rs,8);
            l_run[reg] = l_run[reg]*scl + rs;
            accO[0][reg] *= scl; accO[1][reg] *= scl;
            accO[2][reg] *= scl; accO[3][reg] *= scl;
            const int prow = w*16 + h16*4 + reg;
            PsS[prow][ 0+l16] = f2bf(p0);
            PsS[prow][16+l16] = f2bf(p1);
            PsS[prow][32+l16] = f2bf(p2);
            PsS[prow][48+l16] = f2bf(p3);
        }

        // O += P V  (PsS rows wave-private)
#pragma unroll
        for (int c=0;c<2;c++){
            const bf16x8 pa = *(const bf16x8*)&PsS[w*16+l16][c*32+8*h16];
#pragma unroll
            for (int j=0;j<4;j++){
                const bf16x8 vb_ = *(const bf16x8*)&VtS[j*16+l16][c*32+8*h16];
                accO[j] = __builtin_amdgcn_mfma_f32_16x16x32_bf16(pa, vb_, accO[j], 0,0,0);
            }
        }
    }

#pragma unroll
    for (int reg=0;reg<4;reg++){
        const float inv = 1.0f / l_run[reg];
        const int t = qb*64 + w*16 + h16*4 + reg;
#pragma unroll
        for (int j=0;j<4;j++){
            attb[((size_t)b*T_ + t)*D_ + h*HD_ + j*16 + l16] =
                f2bf(accO[j][reg]*inv);
        }
    }
}

extern "C" void kernel_launch(void* const* d_in, const int* in_sizes, int n_in,
                              void* d_out, int out_size, void* d_ws, size_t ws_size,
                              hipStream_t stream)
{
    const float* x  = (const float*)d_in[0];
    const float* Wq = (const float*)d_in[1];
    const float* bq = (const float*)d_in[2];
    const float* Wk = (const float*)d_in[3];
    const float* bk = (const float*)d_in[4];
    const float* Wv = (const float*)d_in[5];
    const float* bv = (const float*)d_in[6];
    const float* Wo = (const float*)d_in[7];
    const float* bo = (const float*)d_in[8];
    const int* mask = (const int*)d_in[9];
    float* out = (float*)d_out;

    // workspace (126 MiB): all bf16
    unsigned short* qhp = (unsigned short*)d_ws;                 // 16 MiB
    unsigned short* qlp = qhp + (size_t)8*1024*1024;             // 16 MiB
    unsigned short* khp = qlp + (size_t)8*1024*1024;             // 16 MiB
    unsigned short* klp = khp + (size_t)8*1024*1024;             // 16 MiB
    unsigned short* vtp = klp + (size_t)8*1024*1024;             // 16 MiB [bh][d][t]
    unsigned short* xh  = vtp + (size_t)8*1024*1024;             // 16 MiB
    unsigned short* xl  = xh  + (size_t)8*1024*1024;             // 16 MiB
    unsigned short* wh  = xl  + (size_t)8*1024*1024;             // 6 MiB
    unsigned short* wl  = wh  + (size_t)3*1024*1024;             // 6 MiB
    unsigned short* wot = wl  + (size_t)3*1024*1024;             // 2 MiB
    unsigned short* attb = xh;   // alias: xh dead after gemm_qkv3

    prep_x2   <<<2048, 256, 0, stream>>>(x, xh, xl);
    prep_wqkv2<<<dim3(16,48), 256, 0, stream>>>(Wq, Wk, Wv, wh, wl);
    prep_wo   <<<dim3(16,16), 256, 0, stream>>>(Wo, wot);
    gemm_qkv3 <<<dim3(64,24), 256, 0, stream>>>(xh, xl, wh, wl, bq, bk, bv,
                                                qhp, qlp, khp, klp, vtp);
    attn_mfma <<<2048, 256, 0, stream>>>(qhp, qlp, khp, klp, vtp, attb, mask);
    gemm_o    <<<dim3(64,8), 256, 0, stream>>>(attb, wot, bo, out);
}

// Round 15
// 215.355 us; speedup vs baseline: 1.9489x; 1.4573x over previous
//
#include <hip/hip_runtime.h>
#include <hip/hip_bf16.h>
#include <math.h>

#define B_  4
#define T_  2048
#define D_  1024
#define H_  16
#define HD_ 64
#define M_  8192   // B_*T_

typedef __attribute__((ext_vector_type(8))) _Float16 f16x8;
typedef __attribute__((ext_vector_type(4))) float   f32x4;

static __device__ __forceinline__ unsigned short f2h(float f){
    union { _Float16 h; unsigned short u; } cv; cv.h = (_Float16)f; return cv.u;
}
static __device__ __forceinline__ void gload_lds16(const void* g, void* l){
    __builtin_amdgcn_global_load_lds(
        (const __attribute__((address_space(1))) unsigned int*)g,
        (__attribute__((address_space(3))) unsigned int*)l, 16, 0, 0);
}

union U16x16 { unsigned short us[16]; uint4 q[2]; };
union U16x4  { unsigned short us[4];  uint2 q;    };

// ---------------------------------------------------------------------------
// prep_xh: x fp32 [8192][1024] -> xb fp16. 16 el/thread.
// ---------------------------------------------------------------------------
__global__ __launch_bounds__(256) void prep_xh(
    const float* __restrict__ x, unsigned short* __restrict__ xb)
{
    const size_t i = ((size_t)blockIdx.x*256 + threadIdx.x)*16;
    U16x16 u;
#pragma unroll
    for (int j=0;j<16;j+=4){
        float4 f = *(const float4*)(x+i+j);
        u.us[j+0]=f2h(f.x); u.us[j+1]=f2h(f.y);
        u.us[j+2]=f2h(f.z); u.us[j+3]=f2h(f.w);
    }
    *(uint4*)(xb+i)   = u.q[0];
    *(uint4*)(xb+i+8) = u.q[1];
}

// ---------------------------------------------------------------------------
// prep_wqkvh: W{q,k,v}[16][1024][64] -> wt[3072][1024] fp16 (operand-major).
// ---------------------------------------------------------------------------
__global__ __launch_bounds__(256) void prep_wqkvh(
    const float* __restrict__ Wq, const float* __restrict__ Wk,
    const float* __restrict__ Wv, unsigned short* __restrict__ wt)
{
    const int dt = blockIdx.x;
    const int zh = blockIdx.y;
    const int z = zh >> 4, h = zh & 15;
    const float* src = ((z==0)?Wq:(z==1)?Wk:Wv) + (size_t)h*1024*64;
    __shared__ float Tt[64][68];
    const int t = threadIdx.x;
    const int r = t >> 2, c4 = (t & 3) * 16;
    const float* sp = src + (size_t)(dt*64 + r)*64 + c4;
    float4 v0=*(const float4*)(sp+0), v1=*(const float4*)(sp+4);
    float4 v2=*(const float4*)(sp+8), v3=*(const float4*)(sp+12);
    *(float4*)&Tt[r][c4+ 0]=v0; *(float4*)&Tt[r][c4+ 4]=v1;
    *(float4*)&Tt[r][c4+ 8]=v2; *(float4*)&Tt[r][c4+12]=v3;
    __syncthreads();
    const int er = t >> 2, dk = (t & 3) * 16;
    U16x16 u;
#pragma unroll
    for (int j=0;j<16;j++) u.us[j] = f2h(Tt[dk+j][er]);
    unsigned short* dst = wt + (size_t)(z*1024 + h*64 + er)*1024 + dt*64 + dk;
    *(uint4*)(dst)   = u.q[0];
    *(uint4*)(dst+8) = u.q[1];
}

// ---------------------------------------------------------------------------
// prep_woh: Wo[1024][1024] -> wot[n][k] fp16.
// ---------------------------------------------------------------------------
__global__ __launch_bounds__(256) void prep_woh(
    const float* __restrict__ Wo, unsigned short* __restrict__ wot)
{
    const int kt = blockIdx.x, nt = blockIdx.y;
    __shared__ float Tt[64][68];
    const int t = threadIdx.x;
    const int r = t >> 2, c4 = (t & 3) * 16;
    const float* sp = Wo + (size_t)(kt*64 + r)*1024 + nt*64 + c4;
    float4 v0=*(const float4*)(sp+0), v1=*(const float4*)(sp+4);
    float4 v2=*(const float4*)(sp+8), v3=*(const float4*)(sp+12);
    *(float4*)&Tt[r][c4+ 0]=v0; *(float4*)&Tt[r][c4+ 4]=v1;
    *(float4*)&Tt[r][c4+ 8]=v2; *(float4*)&Tt[r][c4+12]=v3;
    __syncthreads();
    const int er = t >> 2, dk = (t & 3) * 16;
    U16x16 u;
#pragma unroll
    for (int j=0;j<16;j++) u.us[j] = f2h(Tt[dk+j][er]);
    unsigned short* dst = wot + (size_t)(nt*64 + er)*1024 + kt*64 + dk;
    *(uint4*)(dst)   = u.q[0];
    *(uint4*)(dst+8) = u.q[1];
}

// ---------------------------------------------------------------------------
// gemm_qkvh: C[128x128]/block, 4 waves, 64x64/wave, fp16 16x16x32 MFMA,
// single product everywhere (fp16 precision replaces bf16x3 split).
// R10-proven staging: single-buffer global_load_lds(16B) + chunk-XOR swizzle
// via pre-swizzled source (0 bank conflicts). 16KB LDS.
// Outputs: q (x8 scale) / k row-major fp16; v TRANSPOSED [bh][d][t] fp16.
// ---------------------------------------------------------------------------
__global__ __launch_bounds__(256) void gemm_qkvh(
    const unsigned short* __restrict__ xb, const unsigned short* __restrict__ wt,
    const float* __restrict__ bqv, const float* __restrict__ bkv,
    const float* __restrict__ bvv,
    unsigned short* __restrict__ qp, unsigned short* __restrict__ kp,
    unsigned short* __restrict__ vtp)
{
    const int m0 = blockIdx.x * 128;
    const int n0 = blockIdx.y * 128;
    const int tid = threadIdx.x;
    const int lane = tid & 63, w = tid >> 6;
    const int wr = w >> 1, wc = w & 1;
    const int fla = lane & 15, flb = lane >> 4;

    __shared__ unsigned short As[128*32];
    __shared__ unsigned short Bs[128*32];

    f32x4 acc[4][4];
#pragma unroll
    for (int i=0;i<4;i++)
#pragma unroll
        for (int j=0;j<4;j++) acc[i][j] = (f32x4){0.f,0.f,0.f,0.f};

    const int srow0 = w*32 + (lane>>2);
    const int srow1 = srow0 + 16;
    const int spc   = lane & 3;
    const size_t ga0 = (size_t)(m0+srow0)*1024 + (size_t)((spc ^ ((srow0>>1)&3))*8);
    const size_t ga1 = (size_t)(m0+srow1)*1024 + (size_t)((spc ^ ((srow1>>1)&3))*8);
    const size_t gb0 = (size_t)(n0+srow0)*1024 + (size_t)((spc ^ ((srow0>>1)&3))*8);
    const size_t gb1 = (size_t)(n0+srow1)*1024 + (size_t)((spc ^ ((srow1>>1)&3))*8);
    const int ldso0 = w*1024;          // shorts
    const int ldso1 = w*1024 + 512;
    const int pchunk = (flb ^ ((fla>>1)&3)) * 8;

    for (int ks = 0; ks < 32; ++ks){
        const size_t k0 = (size_t)ks*32;
        __syncthreads();   // prev chunk's fragment reads complete
        gload_lds16(xb + ga0 + k0, As + ldso0);
        gload_lds16(xb + ga1 + k0, As + ldso1);
        gload_lds16(wt + gb0 + k0, Bs + ldso0);
        gload_lds16(wt + gb1 + k0, Bs + ldso1);
        __syncthreads();   // vmcnt(0) drained at barrier

        f16x8 af[4], bfr[4];
#pragma unroll
        for (int mf=0; mf<4; ++mf)
            af[mf] = *(const f16x8*)&As[(wr*64+mf*16+fla)*32 + pchunk];
#pragma unroll
        for (int nf=0; nf<4; ++nf)
            bfr[nf] = *(const f16x8*)&Bs[(wc*64+nf*16+fla)*32 + pchunk];
#pragma unroll
        for (int mf=0; mf<4; ++mf)
#pragma unroll
            for (int nf=0; nf<4; ++nf)
                acc[mf][nf] = __builtin_amdgcn_mfma_f32_16x16x32_f16(
                                  af[mf], bfr[nf], acc[mf][nf], 0, 0, 0);
    }

#pragma unroll
    for (int nf=0; nf<4; ++nf){
        const int c = n0 + wc*64 + nf*16 + fla;
        const int z = c >> 10, rem = c & 1023;   // z uniform across lanes per nf
        const int h = rem >> 6, e = rem & 63;
        if (z < 2){
            const float bias = ((z==0)?bqv:bkv)[rem];
            const float scl  = (z==0) ? 8.0f : 1.0f;
            unsigned short* op = (z==0)?qp:kp;
#pragma unroll
            for (int mf=0; mf<4; ++mf){
#pragma unroll
                for (int ri=0; ri<4; ++ri){
                    const int m = m0 + wr*64 + mf*16 + flb*4 + ri;
                    const int b = m >> 11, t = m & (T_-1);
                    op[((size_t)(b*H_ + h)*T_ + t)*HD_ + e] =
                        f2h((acc[mf][nf][ri] + bias) * scl);
                }
            }
        } else {
            const float bias = bvv[rem];
#pragma unroll
            for (int mf=0; mf<4; ++mf){
                const int m = m0 + wr*64 + mf*16 + flb*4;   // 4 consecutive t
                const int b = m >> 11, t = m & (T_-1);
                U16x4 u;
#pragma unroll
                for (int ri=0; ri<4; ++ri)
                    u.us[ri] = f2h(acc[mf][nf][ri] + bias);
                *(uint2*)(vtp + ((size_t)(b*H_ + h)*HD_ + e)*T_ + t) = u.q;
            }
        }
    }
}

// ---------------------------------------------------------------------------
// gemm_o: out = att(fp16) @ wot(fp16) + bo. Single-buffer gload_lds + swizzle.
// ---------------------------------------------------------------------------
__global__ __launch_bounds__(256) void gemm_o(
    const unsigned short* __restrict__ attb, const unsigned short* __restrict__ wot,
    const float* __restrict__ bo, float* __restrict__ out)
{
    const int m0 = blockIdx.x * 128;
    const int n0 = blockIdx.y * 128;
    const int tid = threadIdx.x;
    const int lane = tid & 63, w = tid >> 6;
    const int wr = w >> 1, wc = w & 1;
    const int fla = lane & 15, flb = lane >> 4;

    __shared__ unsigned short As[4096];
    __shared__ unsigned short Bs[4096];

    f32x4 acc[4][4];
#pragma unroll
    for (int i=0;i<4;i++)
#pragma unroll
        for (int j=0;j<4;j++) acc[i][j] = (f32x4){0.f,0.f,0.f,0.f};

    const int srow0 = w*32 + (lane>>2);
    const int srow1 = srow0 + 16;
    const int spc   = lane & 3;
    const size_t ga0 = (size_t)(m0+srow0)*1024 + (size_t)((spc ^ ((srow0>>1)&3))*8);
    const size_t ga1 = (size_t)(m0+srow1)*1024 + (size_t)((spc ^ ((srow1>>1)&3))*8);
    const size_t gb0 = (size_t)(n0+srow0)*1024 + (size_t)((spc ^ ((srow0>>1)&3))*8);
    const size_t gb1 = (size_t)(n0+srow1)*1024 + (size_t)((spc ^ ((srow1>>1)&3))*8);
    const int ldso0 = w*1024;
    const int ldso1 = w*1024 + 512;
    const int pchunk = (flb ^ ((fla>>1)&3)) * 8;

    for (int ks = 0; ks < 32; ++ks){
        const size_t k0 = (size_t)ks*32;
        __syncthreads();
        gload_lds16(attb + ga0 + k0, As + ldso0);
        gload_lds16(attb + ga1 + k0, As + ldso1);
        gload_lds16(wot  + gb0 + k0, Bs + ldso0);
        gload_lds16(wot  + gb1 + k0, Bs + ldso1);
        __syncthreads();

        f16x8 af[4], bfr[4];
#pragma unroll
        for (int mf=0; mf<4; ++mf)
            af[mf] = *(const f16x8*)&As[(wr*64+mf*16+fla)*32 + pchunk];
#pragma unroll
        for (int nf=0; nf<4; ++nf)
            bfr[nf] = *(const f16x8*)&Bs[(wc*64+nf*16+fla)*32 + pchunk];
#pragma unroll
        for (int mf=0; mf<4; ++mf)
#pragma unroll
            for (int nf=0; nf<4; ++nf)
                acc[mf][nf] = __builtin_amdgcn_mfma_f32_16x16x32_f16(
                                  af[mf], bfr[nf], acc[mf][nf], 0, 0, 0);
    }

#pragma unroll
    for (int nf=0; nf<4; ++nf){
        const int n = n0 + wc*64 + nf*16 + fla;
        const float bias = bo[n];
#pragma unroll
        for (int mf=0; mf<4; ++mf){
#pragma unroll
            for (int ri=0; ri<4; ++ri){
                const int m = m0 + wr*64 + mf*16 + flb*4 + ri;
                out[(size_t)m*D_ + n] = acc[mf][nf][ri] + bias;
            }
        }
    }
}

// ---------------------------------------------------------------------------
// MFMA flash attention, fp16 operands (fp32 softmax/accum unchanged).
// One block = (b,h) x 64 q-rows; 4 waves x 16 rows. QK^T: single fp16
// product (2 MFMAs/j). PV: fp16 P x fp16 V^T. LDS 3x[64][72] fp16 = 27KB.
// ---------------------------------------------------------------------------
__global__ __launch_bounds__(256) void attn_mfma(
    const unsigned short* __restrict__ qp, const unsigned short* __restrict__ kp,
    const unsigned short* __restrict__ vtp, unsigned short* __restrict__ attb,
    const int* __restrict__ maskp)
{
    const int bid = blockIdx.x;
    const int qb  = 31 - (bid >> 6);   // big blocks first
    const int bh  = bid & 63;
    const int b   = bh >> 4, h = bh & 15;
    const int tid = threadIdx.x;
    const int lane = tid & 63, w = tid >> 6;
    const int l16 = lane & 15, h16 = lane >> 4;
    const int domask = maskp[0];

    __shared__ unsigned short KS [64][72];
    __shared__ unsigned short VtS[64][72];   // [d][key]
    __shared__ unsigned short PsS[64][72];   // wave-private rows

    const int qrow = qb*64 + w*16 + l16;
    const size_t qoff = ((size_t)bh*T_ + qrow)*HD_ + 8*h16;
    const f16x8 q0 = *(const f16x8*)(qp + qoff);
    const f16x8 q1 = *(const f16x8*)(qp + qoff + 32);

    f32x4 accO[4];
#pragma unroll
    for (int j=0;j<4;j++) accO[j] = (f32x4){0.f,0.f,0.f,0.f};
    float m_run[4], l_run[4];
#pragma unroll
    for (int i=0;i<4;i++){ m_run[i] = -INFINITY; l_run[i] = 0.f; }

    const int r   = tid >> 2;         // staging row 0..63
    const int c16 = (tid & 3) * 16;   // staging col base
    const size_t kbase = (size_t)bh*T_*HD_;
    const size_t vbase = (size_t)bh*HD_*T_;

    const int kv_end = domask ? qb : 31;
    for (int kv = 0; kv <= kv_end; ++kv){
        const unsigned short* ksrc = kp + kbase + (size_t)(kv*64+r)*HD_ + c16;
        uint4 a0 = *(const uint4*)(ksrc);
        uint4 a1 = *(const uint4*)(ksrc+8);
        const unsigned short* vsrc = vtp + vbase + (size_t)r*T_ + kv*64 + c16;
        uint4 a4 = *(const uint4*)(vsrc);
        uint4 a5 = *(const uint4*)(vsrc+8);
        __syncthreads();   // prev tile reads done
        *(uint4*)&KS [r][c16] = a0; *(uint4*)&KS [r][c16+8] = a1;
        *(uint4*)&VtS[r][c16] = a4; *(uint4*)&VtS[r][c16+8] = a5;
        __syncthreads();

        // S = Q K^T (fp16 single product)
        f32x4 s[4];
#pragma unroll
        for (int j=0;j<4;j++){
            const f16x8 k0 = *(const f16x8*)&KS[j*16+l16][8*h16];
            const f16x8 k1 = *(const f16x8*)&KS[j*16+l16][32+8*h16];
            f32x4 a = (f32x4){0.f,0.f,0.f,0.f};
            a = __builtin_amdgcn_mfma_f32_16x16x32_f16(q0, k0, a, 0,0,0);
            a = __builtin_amdgcn_mfma_f32_16x16x32_f16(q1, k1, a, 0,0,0);
            s[j] = a;
        }
        if (domask && kv == qb){
#pragma unroll
            for (int j=0;j<4;j++)
#pragma unroll
                for (int reg=0;reg<4;reg++)
                    if (j*16+l16 > w*16 + h16*4 + reg) s[j][reg] = -INFINITY;
        }

        // online softmax; rows = w*16 + h16*4 + reg
#pragma unroll
        for (int reg=0; reg<4; ++reg){
            float mloc = fmaxf(fmaxf(s[0][reg],s[1][reg]), fmaxf(s[2][reg],s[3][reg]));
            mloc = fmaxf(mloc, __shfl_xor(mloc,1));
            mloc = fmaxf(mloc, __shfl_xor(mloc,2));
            mloc = fmaxf(mloc, __shfl_xor(mloc,4));
            mloc = fmaxf(mloc, __shfl_xor(mloc,8));
            float mnew = fmaxf(m_run[reg], mloc);
            float scl  = __expf(m_run[reg] - mnew);   // exp(-inf)=0 first tile
            m_run[reg] = mnew;
            float p0 = __expf(s[0][reg]-mnew);
            float p1 = __expf(s[1][reg]-mnew);
            float p2 = __expf(s[2][reg]-mnew);
            float p3 = __expf(s[3][reg]-mnew);
            float rs = p0+p1+p2+p3;
            rs += __shfl_xor(rs,1); rs += __shfl_xor(rs,2);
            rs += __shfl_xor(rs,4); rs += __shfl_xor(rs,8);
            l_run[reg] = l_run[reg]*scl + rs;
            accO[0][reg] *= scl; accO[1][reg] *= scl;
            accO[2][reg] *= scl; accO[3][reg] *= scl;
            const int prow = w*16 + h16*4 + reg;
            PsS[prow][ 0+l16] = f2h(p0);
            PsS[prow][16+l16] = f2h(p1);
            PsS[prow][32+l16] = f2h(p2);
            PsS[prow][48+l16] = f2h(p3);
        }

        // O += P V  (PsS rows wave-private)
#pragma unroll
        for (int c=0;c<2;c++){
            const f16x8 pa = *(const f16x8*)&PsS[w*16+l16][c*32+8*h16];
#pragma unroll
            for (int j=0;j<4;j++){
                const f16x8 vb_ = *(const f16x8*)&VtS[j*16+l16][c*32+8*h16];
                accO[j] = __builtin_amdgcn_mfma_f32_16x16x32_f16(pa, vb_, accO[j], 0,0,0);
            }
        }
    }

#pragma unroll
    for (int reg=0;reg<4;reg++){
        const float inv = 1.0f / l_run[reg];
        const int t = qb*64 + w*16 + h16*4 + reg;
#pragma unroll
        for (int j=0;j<4;j++){
            attb[((size_t)b*T_ + t)*D_ + h*HD_ + j*16 + l16] =
                f2h(accO[j][reg]*inv);
        }
    }
}

extern "C" void kernel_launch(void* const* d_in, const int* in_sizes, int n_in,
                              void* d_out, int out_size, void* d_ws, size_t ws_size,
                              hipStream_t stream)
{
    const float* x  = (const float*)d_in[0];
    const float* Wq = (const float*)d_in[1];
    const float* bq = (const float*)d_in[2];
    const float* Wk = (const float*)d_in[3];
    const float* bk = (const float*)d_in[4];
    const float* Wv = (const float*)d_in[5];
    const float* bv = (const float*)d_in[6];
    const float* Wo = (const float*)d_in[7];
    const float* bo = (const float*)d_in[8];
    const int* mask = (const int*)d_in[9];
    float* out = (float*)d_out;

    // workspace (72 MiB): all fp16
    unsigned short* qp  = (unsigned short*)d_ws;                 // 16 MiB
    unsigned short* kp  = qp  + (size_t)8*1024*1024;             // 16 MiB
    unsigned short* vtp = kp  + (size_t)8*1024*1024;             // 16 MiB [bh][d][t]
    unsigned short* xb  = vtp + (size_t)8*1024*1024;             // 16 MiB
    unsigned short* wt  = xb  + (size_t)8*1024*1024;             // 6 MiB
    unsigned short* wot = wt  + (size_t)3*1024*1024;             // 2 MiB
    unsigned short* attb = xb;   // alias: xb dead after gemm_qkvh

    prep_xh   <<<2048, 256, 0, stream>>>(x, xb);
    prep_wqkvh<<<dim3(16,48), 256, 0, stream>>>(Wq, Wk, Wv, wt);
    prep_woh  <<<dim3(16,16), 256, 0, stream>>>(Wo, wot);
    gemm_qkvh <<<dim3(64,24), 256, 0, stream>>>(xb, wt, bq, bk, bv, qp, kp, vtp);
    attn_mfma <<<2048, 256, 0, stream>>>(qp, kp, vtp, attb, mask);
    gemm_o    <<<dim3(64,8), 256, 0, stream>>>(attb, wot, bo, out);
}

// Round 16
// 215.214 us; speedup vs baseline: 1.9501x; 1.0007x over previous
//
#include <hip/hip_runtime.h>
#include <hip/hip_bf16.h>
#include <math.h>

#define B_  4
#define T_  2048
#define D_  1024
#define H_  16
#define HD_ 64
#define M_  8192   // B_*T_

typedef __attribute__((ext_vector_type(8))) _Float16 f16x8;
typedef __attribute__((ext_vector_type(4))) float   f32x4;

static __device__ __forceinline__ unsigned short f2h(float f){
    union { _Float16 h; unsigned short u; } cv; cv.h = (_Float16)f; return cv.u;
}
static __device__ __forceinline__ void gload_lds16(const void* g, void* l){
    __builtin_amdgcn_global_load_lds(
        (const __attribute__((address_space(1))) unsigned int*)g,
        (__attribute__((address_space(3))) unsigned int*)l, 16, 0, 0);
}

union U16x16 { unsigned short us[16]; uint4 q[2]; };
union U16x4  { unsigned short us[4];  uint2 q;    };

// ---------------------------------------------------------------------------
// prep_xh: x fp32 [8192][1024] -> xb fp16. 16 el/thread.
// ---------------------------------------------------------------------------
__global__ __launch_bounds__(256) void prep_xh(
    const float* __restrict__ x, unsigned short* __restrict__ xb)
{
    const size_t i = ((size_t)blockIdx.x*256 + threadIdx.x)*16;
    U16x16 u;
#pragma unroll
    for (int j=0;j<16;j+=4){
        float4 f = *(const float4*)(x+i+j);
        u.us[j+0]=f2h(f.x); u.us[j+1]=f2h(f.y);
        u.us[j+2]=f2h(f.z); u.us[j+3]=f2h(f.w);
    }
    *(uint4*)(xb+i)   = u.q[0];
    *(uint4*)(xb+i+8) = u.q[1];
}

// ---------------------------------------------------------------------------
// prep_wqkvh: W{q,k,v}[16][1024][64] -> wt[3072][1024] fp16 (operand-major).
// ---------------------------------------------------------------------------
__global__ __launch_bounds__(256) void prep_wqkvh(
    const float* __restrict__ Wq, const float* __restrict__ Wk,
    const float* __restrict__ Wv, unsigned short* __restrict__ wt)
{
    const int dt = blockIdx.x;
    const int zh = blockIdx.y;
    const int z = zh >> 4, h = zh & 15;
    const float* src = ((z==0)?Wq:(z==1)?Wk:Wv) + (size_t)h*1024*64;
    __shared__ float Tt[64][68];
    const int t = threadIdx.x;
    const int r = t >> 2, c4 = (t & 3) * 16;
    const float* sp = src + (size_t)(dt*64 + r)*64 + c4;
    float4 v0=*(const float4*)(sp+0), v1=*(const float4*)(sp+4);
    float4 v2=*(const float4*)(sp+8), v3=*(const float4*)(sp+12);
    *(float4*)&Tt[r][c4+ 0]=v0; *(float4*)&Tt[r][c4+ 4]=v1;
    *(float4*)&Tt[r][c4+ 8]=v2; *(float4*)&Tt[r][c4+12]=v3;
    __syncthreads();
    const int er = t >> 2, dk = (t & 3) * 16;
    U16x16 u;
#pragma unroll
    for (int j=0;j<16;j++) u.us[j] = f2h(Tt[dk+j][er]);
    unsigned short* dst = wt + (size_t)(z*1024 + h*64 + er)*1024 + dt*64 + dk;
    *(uint4*)(dst)   = u.q[0];
    *(uint4*)(dst+8) = u.q[1];
}

// ---------------------------------------------------------------------------
// prep_woh: Wo[1024][1024] -> wot[n][k] fp16.
// ---------------------------------------------------------------------------
__global__ __launch_bounds__(256) void prep_woh(
    const float* __restrict__ Wo, unsigned short* __restrict__ wot)
{
    const int kt = blockIdx.x, nt = blockIdx.y;
    __shared__ float Tt[64][68];
    const int t = threadIdx.x;
    const int r = t >> 2, c4 = (t & 3) * 16;
    const float* sp = Wo + (size_t)(kt*64 + r)*1024 + nt*64 + c4;
    float4 v0=*(const float4*)(sp+0), v1=*(const float4*)(sp+4);
    float4 v2=*(const float4*)(sp+8), v3=*(const float4*)(sp+12);
    *(float4*)&Tt[r][c4+ 0]=v0; *(float4*)&Tt[r][c4+ 4]=v1;
    *(float4*)&Tt[r][c4+ 8]=v2; *(float4*)&Tt[r][c4+12]=v3;
    __syncthreads();
    const int er = t >> 2, dk = (t & 3) * 16;
    U16x16 u;
#pragma unroll
    for (int j=0;j<16;j++) u.us[j] = f2h(Tt[dk+j][er]);
    unsigned short* dst = wot + (size_t)(nt*64 + er)*1024 + kt*64 + dk;
    *(uint4*)(dst)   = u.q[0];
    *(uint4*)(dst+8) = u.q[1];
}

// ---------------------------------------------------------------------------
// gemm_qkvh: unchanged from R15 except q scale folds log2(e):
// scl_q = 8*log2(e) -> attn softmax runs in exp2 domain.
// ---------------------------------------------------------------------------
__global__ __launch_bounds__(256) void gemm_qkvh(
    const unsigned short* __restrict__ xb, const unsigned short* __restrict__ wt,
    const float* __restrict__ bqv, const float* __restrict__ bkv,
    const float* __restrict__ bvv,
    unsigned short* __restrict__ qp, unsigned short* __restrict__ kp,
    unsigned short* __restrict__ vtp)
{
    const int m0 = blockIdx.x * 128;
    const int n0 = blockIdx.y * 128;
    const int tid = threadIdx.x;
    const int lane = tid & 63, w = tid >> 6;
    const int wr = w >> 1, wc = w & 1;
    const int fla = lane & 15, flb = lane >> 4;

    __shared__ unsigned short As[128*32];
    __shared__ unsigned short Bs[128*32];

    f32x4 acc[4][4];
#pragma unroll
    for (int i=0;i<4;i++)
#pragma unroll
        for (int j=0;j<4;j++) acc[i][j] = (f32x4){0.f,0.f,0.f,0.f};

    const int srow0 = w*32 + (lane>>2);
    const int srow1 = srow0 + 16;
    const int spc   = lane & 3;
    const size_t ga0 = (size_t)(m0+srow0)*1024 + (size_t)((spc ^ ((srow0>>1)&3))*8);
    const size_t ga1 = (size_t)(m0+srow1)*1024 + (size_t)((spc ^ ((srow1>>1)&3))*8);
    const size_t gb0 = (size_t)(n0+srow0)*1024 + (size_t)((spc ^ ((srow0>>1)&3))*8);
    const size_t gb1 = (size_t)(n0+srow1)*1024 + (size_t)((spc ^ ((srow1>>1)&3))*8);
    const int ldso0 = w*1024;          // shorts
    const int ldso1 = w*1024 + 512;
    const int pchunk = (flb ^ ((fla>>1)&3)) * 8;

    for (int ks = 0; ks < 32; ++ks){
        const size_t k0 = (size_t)ks*32;
        __syncthreads();   // prev chunk's fragment reads complete
        gload_lds16(xb + ga0 + k0, As + ldso0);
        gload_lds16(xb + ga1 + k0, As + ldso1);
        gload_lds16(wt + gb0 + k0, Bs + ldso0);
        gload_lds16(wt + gb1 + k0, Bs + ldso1);
        __syncthreads();   // vmcnt(0) drained at barrier

        f16x8 af[4], bfr[4];
#pragma unroll
        for (int mf=0; mf<4; ++mf)
            af[mf] = *(const f16x8*)&As[(wr*64+mf*16+fla)*32 + pchunk];
#pragma unroll
        for (int nf=0; nf<4; ++nf)
            bfr[nf] = *(const f16x8*)&Bs[(wc*64+nf*16+fla)*32 + pchunk];
#pragma unroll
        for (int mf=0; mf<4; ++mf)
#pragma unroll
            for (int nf=0; nf<4; ++nf)
                acc[mf][nf] = __builtin_amdgcn_mfma_f32_16x16x32_f16(
                                  af[mf], bfr[nf], acc[mf][nf], 0, 0, 0);
    }

#pragma unroll
    for (int nf=0; nf<4; ++nf){
        const int c = n0 + wc*64 + nf*16 + fla;
        const int z = c >> 10, rem = c & 1023;
        const int h = rem >> 6, e = rem & 63;
        if (z < 2){
            const float bias = ((z==0)?bqv:bkv)[rem];
            const float scl  = (z==0) ? 11.541560327111708f   // 8*log2(e)
                                      : 1.0f;
            unsigned short* op = (z==0)?qp:kp;
#pragma unroll
            for (int mf=0; mf<4; ++mf){
#pragma unroll
                for (int ri=0; ri<4; ++ri){
                    const int m = m0 + wr*64 + mf*16 + flb*4 + ri;
                    const int b = m >> 11, t = m & (T_-1);
                    op[((size_t)(b*H_ + h)*T_ + t)*HD_ + e] =
                        f2h((acc[mf][nf][ri] + bias) * scl);
                }
            }
        } else {
            const float bias = bvv[rem];
#pragma unroll
            for (int mf=0; mf<4; ++mf){
                const int m = m0 + wr*64 + mf*16 + flb*4;   // 4 consecutive t
                const int b = m >> 11, t = m & (T_-1);
                U16x4 u;
#pragma unroll
                for (int ri=0; ri<4; ++ri)
                    u.us[ri] = f2h(acc[mf][nf][ri] + bias);
                *(uint2*)(vtp + ((size_t)(b*H_ + h)*HD_ + e)*T_ + t) = u.q;
            }
        }
    }
}

// ---------------------------------------------------------------------------
// gemm_o: out = att(fp16) @ wot(fp16) + bo. (unchanged from R15)
// ---------------------------------------------------------------------------
__global__ __launch_bounds__(256) void gemm_o(
    const unsigned short* __restrict__ attb, const unsigned short* __restrict__ wot,
    const float* __restrict__ bo, float* __restrict__ out)
{
    const int m0 = blockIdx.x * 128;
    const int n0 = blockIdx.y * 128;
    const int tid = threadIdx.x;
    const int lane = tid & 63, w = tid >> 6;
    const int wr = w >> 1, wc = w & 1;
    const int fla = lane & 15, flb = lane >> 4;

    __shared__ unsigned short As[4096];
    __shared__ unsigned short Bs[4096];

    f32x4 acc[4][4];
#pragma unroll
    for (int i=0;i<4;i++)
#pragma unroll
        for (int j=0;j<4;j++) acc[i][j] = (f32x4){0.f,0.f,0.f,0.f};

    const int srow0 = w*32 + (lane>>2);
    const int srow1 = srow0 + 16;
    const int spc   = lane & 3;
    const size_t ga0 = (size_t)(m0+srow0)*1024 + (size_t)((spc ^ ((srow0>>1)&3))*8);
    const size_t ga1 = (size_t)(m0+srow1)*1024 + (size_t)((spc ^ ((srow1>>1)&3))*8);
    const size_t gb0 = (size_t)(n0+srow0)*1024 + (size_t)((spc ^ ((srow0>>1)&3))*8);
    const size_t gb1 = (size_t)(n0+srow1)*1024 + (size_t)((spc ^ ((srow1>>1)&3))*8);
    const int ldso0 = w*1024;
    const int ldso1 = w*1024 + 512;
    const int pchunk = (flb ^ ((fla>>1)&3)) * 8;

    for (int ks = 0; ks < 32; ++ks){
        const size_t k0 = (size_t)ks*32;
        __syncthreads();
        gload_lds16(attb + ga0 + k0, As + ldso0);
        gload_lds16(attb + ga1 + k0, As + ldso1);
        gload_lds16(wot  + gb0 + k0, Bs + ldso0);
        gload_lds16(wot  + gb1 + k0, Bs + ldso1);
        __syncthreads();

        f16x8 af[4], bfr[4];
#pragma unroll
        for (int mf=0; mf<4; ++mf)
            af[mf] = *(const f16x8*)&As[(wr*64+mf*16+fla)*32 + pchunk];
#pragma unroll
        for (int nf=0; nf<4; ++nf)
            bfr[nf] = *(const f16x8*)&Bs[(wc*64+nf*16+fla)*32 + pchunk];
#pragma unroll
        for (int mf=0; mf<4; ++mf)
#pragma unroll
            for (int nf=0; nf<4; ++nf)
                acc[mf][nf] = __builtin_amdgcn_mfma_f32_16x16x32_f16(
                                  af[mf], bfr[nf], acc[mf][nf], 0, 0, 0);
    }

#pragma unroll
    for (int nf=0; nf<4; ++nf){
        const int n = n0 + wc*64 + nf*16 + fla;
        const float bias = bo[n];
#pragma unroll
        for (int mf=0; mf<4; ++mf){
#pragma unroll
            for (int ri=0; ri<4; ++ri){
                const int m = m0 + wr*64 + mf*16 + flb*4 + ri;
                out[(size_t)m*D_ + n] = acc[mf][nf][ri] + bias;
            }
        }
    }
}

// ---------------------------------------------------------------------------
// MFMA flash attention, fp16 operands, exp2-domain softmax (log2e folded
// into q), defer-max rescale (THR=8 in log2 domain -> P <= 256).
// LDS: chunked-XOR layout [2][64][32] per operand (GEMM-proven 0-conflict
// pattern; sub-block sb stored at sb ^ ((row>>1)&3)). 24KB total.
// ---------------------------------------------------------------------------
__global__ __launch_bounds__(256) void attn_mfma(
    const unsigned short* __restrict__ qp, const unsigned short* __restrict__ kp,
    const unsigned short* __restrict__ vtp, unsigned short* __restrict__ attb,
    const int* __restrict__ maskp)
{
    const int bid = blockIdx.x;
    const int qb  = 31 - (bid >> 6);   // big blocks first
    const int bh  = bid & 63;
    const int b   = bh >> 4, h = bh & 15;
    const int tid = threadIdx.x;
    const int lane = tid & 63, w = tid >> 6;
    const int l16 = lane & 15, h16 = lane >> 4;
    const int domask = maskp[0];

    __shared__ unsigned short KS [2][64][32];
    __shared__ unsigned short VtS[2][64][32];   // [key-chunk][d][key%32]
    __shared__ unsigned short PsS[2][64][32];   // wave-private rows

    const int qrow = qb*64 + w*16 + l16;
    const size_t qoff = ((size_t)bh*T_ + qrow)*HD_ + 8*h16;
    const f16x8 q0 = *(const f16x8*)(qp + qoff);
    const f16x8 q1 = *(const f16x8*)(qp + qoff + 32);

    f32x4 accO[4];
#pragma unroll
    for (int j=0;j<4;j++) accO[j] = (f32x4){0.f,0.f,0.f,0.f};
    float m_run[4], l_run[4];
#pragma unroll
    for (int i=0;i<4;i++){ m_run[i] = -INFINITY; l_run[i] = 0.f; }

    // staging geometry: row r, quarter cq covers shorts [cq*16, cq*16+16)
    const int r   = tid >> 2;
    const int cq  = tid & 3;
    const int sci = cq >> 1;          // chunk
    const int sb0 = (cq & 1) * 2;     // first sub-block
    const int fr  = (r >> 1) & 3;     // swizzle key
    const int sd0 = ((sb0  ) ^ fr)*8;
    const int sd1 = ((sb0+1) ^ fr)*8;
    const int c16 = cq * 16;

    // fragment-read swizzle (row = *16 + l16 -> key = (l16>>1)&3)
    const int off = (h16 ^ ((l16>>1)&3)) * 8;

    const size_t kbase = (size_t)bh*T_*HD_;
    const size_t vbase = (size_t)bh*HD_*T_;

    const int kv_end = domask ? qb : 31;
    for (int kv = 0; kv <= kv_end; ++kv){
        const unsigned short* ksrc = kp + kbase + (size_t)(kv*64+r)*HD_ + c16;
        uint4 a0 = *(const uint4*)(ksrc);
        uint4 a1 = *(const uint4*)(ksrc+8);
        const unsigned short* vsrc = vtp + vbase + (size_t)r*T_ + kv*64 + c16;
        uint4 a4 = *(const uint4*)(vsrc);
        uint4 a5 = *(const uint4*)(vsrc+8);
        __syncthreads();   // prev tile reads done
        *(uint4*)&KS [sci][r][sd0] = a0; *(uint4*)&KS [sci][r][sd1] = a1;
        *(uint4*)&VtS[sci][r][sd0] = a4; *(uint4*)&VtS[sci][r][sd1] = a5;
        __syncthreads();

        // S = Q K^T (fp16 single product, exp2-domain logits)
        f32x4 s[4];
#pragma unroll
        for (int j=0;j<4;j++){
            const f16x8 k0 = *(const f16x8*)&KS[0][j*16+l16][off];
            const f16x8 k1 = *(const f16x8*)&KS[1][j*16+l16][off];
            f32x4 a = (f32x4){0.f,0.f,0.f,0.f};
            a = __builtin_amdgcn_mfma_f32_16x16x32_f16(q0, k0, a, 0,0,0);
            a = __builtin_amdgcn_mfma_f32_16x16x32_f16(q1, k1, a, 0,0,0);
            s[j] = a;
        }
        if (domask && kv == qb){
#pragma unroll
            for (int j=0;j<4;j++)
#pragma unroll
                for (int reg=0;reg<4;reg++)
                    if (j*16+l16 > w*16 + h16*4 + reg) s[j][reg] = -INFINITY;
        }

        // row maxima (rows = w*16 + h16*4 + reg)
        float pmax[4];
#pragma unroll
        for (int reg=0; reg<4; ++reg){
            float mloc = fmaxf(fmaxf(s[0][reg],s[1][reg]), fmaxf(s[2][reg],s[3][reg]));
            mloc = fmaxf(mloc, __shfl_xor(mloc,1));
            mloc = fmaxf(mloc, __shfl_xor(mloc,2));
            mloc = fmaxf(mloc, __shfl_xor(mloc,4));
            mloc = fmaxf(mloc, __shfl_xor(mloc,8));
            pmax[reg] = mloc;
        }
        // defer-max: skip rescale when max growth <= 8 (log2 units)
        const bool small = (pmax[0] <= m_run[0]+8.f) && (pmax[1] <= m_run[1]+8.f)
                        && (pmax[2] <= m_run[2]+8.f) && (pmax[3] <= m_run[3]+8.f);
        if (!__all(small)){
#pragma unroll
            for (int reg=0; reg<4; ++reg){
                const float mnew = fmaxf(m_run[reg], pmax[reg]);
                const float scl  = exp2f(m_run[reg] - mnew);  // exp2(-inf)=0 first tile
                m_run[reg] = mnew;
                l_run[reg] *= scl;
                accO[0][reg] *= scl; accO[1][reg] *= scl;
                accO[2][reg] *= scl; accO[3][reg] *= scl;
            }
        }
        // P = exp2(S - m), row-sum, store P (swizzled scalar stores)
        const int sbl = l16 >> 3, pos = l16 & 7;
#pragma unroll
        for (int reg=0; reg<4; ++reg){
            const float mr = m_run[reg];
            float p0 = exp2f(s[0][reg]-mr);
            float p1 = exp2f(s[1][reg]-mr);
            float p2 = exp2f(s[2][reg]-mr);
            float p3 = exp2f(s[3][reg]-mr);
            float rs = p0+p1+p2+p3;
            rs += __shfl_xor(rs,1); rs += __shfl_xor(rs,2);
            rs += __shfl_xor(rs,4); rs += __shfl_xor(rs,8);
            l_run[reg] += rs;
            const int prow = w*16 + h16*4 + reg;
            const int psw  = (prow>>1)&3;
            PsS[0][prow][((sbl  ) ^ psw)*8 + pos] = f2h(p0);
            PsS[0][prow][((sbl+2) ^ psw)*8 + pos] = f2h(p1);
            PsS[1][prow][((sbl  ) ^ psw)*8 + pos] = f2h(p2);
            PsS[1][prow][((sbl+2) ^ psw)*8 + pos] = f2h(p3);
        }

        // O += P V  (PsS rows wave-private; same-wave RAW via lgkmcnt)
#pragma unroll
        for (int c=0;c<2;c++){
            const f16x8 pa = *(const f16x8*)&PsS[c][w*16+l16][off];
#pragma unroll
            for (int j=0;j<4;j++){
                const f16x8 vb_ = *(const f16x8*)&VtS[c][j*16+l16][off];
                accO[j] = __builtin_amdgcn_mfma_f32_16x16x32_f16(pa, vb_, accO[j], 0,0,0);
            }
        }
    }

#pragma unroll
    for (int reg=0;reg<4;reg++){
        const float inv = 1.0f / l_run[reg];
        const int t = qb*64 + w*16 + h16*4 + reg;
#pragma unroll
        for (int j=0;j<4;j++){
            attb[((size_t)b*T_ + t)*D_ + h*HD_ + j*16 + l16] =
                f2h(accO[j][reg]*inv);
        }
    }
}

extern "C" void kernel_launch(void* const* d_in, const int* in_sizes, int n_in,
                              void* d_out, int out_size, void* d_ws, size_t ws_size,
                              hipStream_t stream)
{
    const float* x  = (const float*)d_in[0];
    const float* Wq = (const float*)d_in[1];
    const float* bq = (const float*)d_in[2];
    const float* Wk = (const float*)d_in[3];
    const float* bk = (const float*)d_in[4];
    const float* Wv = (const float*)d_in[5];
    const float* bv = (const float*)d_in[6];
    const float* Wo = (const float*)d_in[7];
    const float* bo = (const float*)d_in[8];
    const int* mask = (const int*)d_in[9];
    float* out = (float*)d_out;

    // workspace (72 MiB): all fp16
    unsigned short* qp  = (unsigned short*)d_ws;                 // 16 MiB
    unsigned short* kp  = qp  + (size_t)8*1024*1024;             // 16 MiB
    unsigned short* vtp = kp  + (size_t)8*1024*1024;             // 16 MiB [bh][d][t]
    unsigned short* xb  = vtp + (size_t)8*1024*1024;             // 16 MiB
    unsigned short* wt  = xb  + (size_t)8*1024*1024;             // 6 MiB
    unsigned short* wot = wt  + (size_t)3*1024*1024;             // 2 MiB
    unsigned short* attb = xb;   // alias: xb dead after gemm_qkvh

    prep_xh   <<<2048, 256, 0, stream>>>(x, xb);
    prep_wqkvh<<<dim3(16,48), 256, 0, stream>>>(Wq, Wk, Wv, wt);
    prep_woh  <<<dim3(16,16), 256, 0, stream>>>(Wo, wot);
    gemm_qkvh <<<dim3(64,24), 256, 0, stream>>>(xb, wt, bq, bk, bv, qp, kp, vtp);
    attn_mfma <<<2048, 256, 0, stream>>>(qp, kp, vtp, attb, mask);
    gemm_o    <<<dim3(64,8), 256, 0, stream>>>(attb, wot, bo, out);
}

// Round 17
// 203.379 us; speedup vs baseline: 2.0636x; 1.0582x over previous
//
#include <hip/hip_runtime.h>
#include <hip/hip_bf16.h>
#include <math.h>

#define B_  4
#define T_  2048
#define D_  1024
#define H_  16
#define HD_ 64
#define M_  8192   // B_*T_

typedef __attribute__((ext_vector_type(8))) _Float16 f16x8;
typedef __attribute__((ext_vector_type(4))) float   f32x4;

static __device__ __forceinline__ unsigned short f2h(float f){
    union { _Float16 h; unsigned short u; } cv; cv.h = (_Float16)f; return cv.u;
}
static __device__ __forceinline__ void gload_lds16(const void* g, void* l){
    __builtin_amdgcn_global_load_lds(
        (const __attribute__((address_space(1))) unsigned int*)g,
        (__attribute__((address_space(3))) unsigned int*)l, 16, 0, 0);
}

union U16x16 { unsigned short us[16]; uint4 q[2]; };
union U16x4  { unsigned short us[4];  uint2 q;    };

// ---------------------------------------------------------------------------
// prep_xh: x fp32 [8192][1024] -> xb fp16. 16 el/thread.
// ---------------------------------------------------------------------------
__global__ __launch_bounds__(256) void prep_xh(
    const float* __restrict__ x, unsigned short* __restrict__ xb)
{
    const size_t i = ((size_t)blockIdx.x*256 + threadIdx.x)*16;
    U16x16 u;
#pragma unroll
    for (int j=0;j<16;j+=4){
        float4 f = *(const float4*)(x+i+j);
        u.us[j+0]=f2h(f.x); u.us[j+1]=f2h(f.y);
        u.us[j+2]=f2h(f.z); u.us[j+3]=f2h(f.w);
    }
    *(uint4*)(xb+i)   = u.q[0];
    *(uint4*)(xb+i+8) = u.q[1];
}

// ---------------------------------------------------------------------------
// prep_wqkvh: W{q,k,v}[16][1024][64] -> wt[3072][1024] fp16 (operand-major).
// ---------------------------------------------------------------------------
__global__ __launch_bounds__(256) void prep_wqkvh(
    const float* __restrict__ Wq, const float* __restrict__ Wk,
    const float* __restrict__ Wv, unsigned short* __restrict__ wt)
{
    const int dt = blockIdx.x;
    const int zh = blockIdx.y;
    const int z = zh >> 4, h = zh & 15;
    const float* src = ((z==0)?Wq:(z==1)?Wk:Wv) + (size_t)h*1024*64;
    __shared__ float Tt[64][68];
    const int t = threadIdx.x;
    const int r = t >> 2, c4 = (t & 3) * 16;
    const float* sp = src + (size_t)(dt*64 + r)*64 + c4;
    float4 v0=*(const float4*)(sp+0), v1=*(const float4*)(sp+4);
    float4 v2=*(const float4*)(sp+8), v3=*(const float4*)(sp+12);
    *(float4*)&Tt[r][c4+ 0]=v0; *(float4*)&Tt[r][c4+ 4]=v1;
    *(float4*)&Tt[r][c4+ 8]=v2; *(float4*)&Tt[r][c4+12]=v3;
    __syncthreads();
    const int er = t >> 2, dk = (t & 3) * 16;
    U16x16 u;
#pragma unroll
    for (int j=0;j<16;j++) u.us[j] = f2h(Tt[dk+j][er]);
    unsigned short* dst = wt + (size_t)(z*1024 + h*64 + er)*1024 + dt*64 + dk;
    *(uint4*)(dst)   = u.q[0];
    *(uint4*)(dst+8) = u.q[1];
}

// ---------------------------------------------------------------------------
// prep_woh: Wo[1024][1024] -> wot[n][k] fp16.
// ---------------------------------------------------------------------------
__global__ __launch_bounds__(256) void prep_woh(
    const float* __restrict__ Wo, unsigned short* __restrict__ wot)
{
    const int kt = blockIdx.x, nt = blockIdx.y;
    __shared__ float Tt[64][68];
    const int t = threadIdx.x;
    const int r = t >> 2, c4 = (t & 3) * 16;
    const float* sp = Wo + (size_t)(kt*64 + r)*1024 + nt*64 + c4;
    float4 v0=*(const float4*)(sp+0), v1=*(const float4*)(sp+4);
    float4 v2=*(const float4*)(sp+8), v3=*(const float4*)(sp+12);
    *(float4*)&Tt[r][c4+ 0]=v0; *(float4*)&Tt[r][c4+ 4]=v1;
    *(float4*)&Tt[r][c4+ 8]=v2; *(float4*)&Tt[r][c4+12]=v3;
    __syncthreads();
    const int er = t >> 2, dk = (t & 3) * 16;
    U16x16 u;
#pragma unroll
    for (int j=0;j<16;j++) u.us[j] = f2h(Tt[dk+j][er]);
    unsigned short* dst = wot + (size_t)(nt*64 + er)*1024 + kt*64 + dk;
    *(uint4*)(dst)   = u.q[0];
    *(uint4*)(dst+8) = u.q[1];
}

// ---------------------------------------------------------------------------
// gemm_qkvh: unchanged from R16 (q scale folds 8*log2(e)).
// ---------------------------------------------------------------------------
__global__ __launch_bounds__(256) void gemm_qkvh(
    const unsigned short* __restrict__ xb, const unsigned short* __restrict__ wt,
    const float* __restrict__ bqv, const float* __restrict__ bkv,
    const float* __restrict__ bvv,
    unsigned short* __restrict__ qp, unsigned short* __restrict__ kp,
    unsigned short* __restrict__ vtp)
{
    const int m0 = blockIdx.x * 128;
    const int n0 = blockIdx.y * 128;
    const int tid = threadIdx.x;
    const int lane = tid & 63, w = tid >> 6;
    const int wr = w >> 1, wc = w & 1;
    const int fla = lane & 15, flb = lane >> 4;

    __shared__ unsigned short As[128*32];
    __shared__ unsigned short Bs[128*32];

    f32x4 acc[4][4];
#pragma unroll
    for (int i=0;i<4;i++)
#pragma unroll
        for (int j=0;j<4;j++) acc[i][j] = (f32x4){0.f,0.f,0.f,0.f};

    const int srow0 = w*32 + (lane>>2);
    const int srow1 = srow0 + 16;
    const int spc   = lane & 3;
    const size_t ga0 = (size_t)(m0+srow0)*1024 + (size_t)((spc ^ ((srow0>>1)&3))*8);
    const size_t ga1 = (size_t)(m0+srow1)*1024 + (size_t)((spc ^ ((srow1>>1)&3))*8);
    const size_t gb0 = (size_t)(n0+srow0)*1024 + (size_t)((spc ^ ((srow0>>1)&3))*8);
    const size_t gb1 = (size_t)(n0+srow1)*1024 + (size_t)((spc ^ ((srow1>>1)&3))*8);
    const int ldso0 = w*1024;          // shorts
    const int ldso1 = w*1024 + 512;
    const int pchunk = (flb ^ ((fla>>1)&3)) * 8;

    for (int ks = 0; ks < 32; ++ks){
        const size_t k0 = (size_t)ks*32;
        __syncthreads();   // prev chunk's fragment reads complete
        gload_lds16(xb + ga0 + k0, As + ldso0);
        gload_lds16(xb + ga1 + k0, As + ldso1);
        gload_lds16(wt + gb0 + k0, Bs + ldso0);
        gload_lds16(wt + gb1 + k0, Bs + ldso1);
        __syncthreads();   // vmcnt(0) drained at barrier

        f16x8 af[4], bfr[4];
#pragma unroll
        for (int mf=0; mf<4; ++mf)
            af[mf] = *(const f16x8*)&As[(wr*64+mf*16+fla)*32 + pchunk];
#pragma unroll
        for (int nf=0; nf<4; ++nf)
            bfr[nf] = *(const f16x8*)&Bs[(wc*64+nf*16+fla)*32 + pchunk];
#pragma unroll
        for (int mf=0; mf<4; ++mf)
#pragma unroll
            for (int nf=0; nf<4; ++nf)
                acc[mf][nf] = __builtin_amdgcn_mfma_f32_16x16x32_f16(
                                  af[mf], bfr[nf], acc[mf][nf], 0, 0, 0);
    }

#pragma unroll
    for (int nf=0; nf<4; ++nf){
        const int c = n0 + wc*64 + nf*16 + fla;
        const int z = c >> 10, rem = c & 1023;
        const int h = rem >> 6, e = rem & 63;
        if (z < 2){
            const float bias = ((z==0)?bqv:bkv)[rem];
            const float scl  = (z==0) ? 11.541560327111708f   // 8*log2(e)
                                      : 1.0f;
            unsigned short* op = (z==0)?qp:kp;
#pragma unroll
            for (int mf=0; mf<4; ++mf){
#pragma unroll
                for (int ri=0; ri<4; ++ri){
                    const int m = m0 + wr*64 + mf*16 + flb*4 + ri;
                    const int b = m >> 11, t = m & (T_-1);
                    op[((size_t)(b*H_ + h)*T_ + t)*HD_ + e] =
                        f2h((acc[mf][nf][ri] + bias) * scl);
                }
            }
        } else {
            const float bias = bvv[rem];
#pragma unroll
            for (int mf=0; mf<4; ++mf){
                const int m = m0 + wr*64 + mf*16 + flb*4;   // 4 consecutive t
                const int b = m >> 11, t = m & (T_-1);
                U16x4 u;
#pragma unroll
                for (int ri=0; ri<4; ++ri)
                    u.us[ri] = f2h(acc[mf][nf][ri] + bias);
                *(uint2*)(vtp + ((size_t)(b*H_ + h)*HD_ + e)*T_ + t) = u.q;
            }
        }
    }
}

// ---------------------------------------------------------------------------
// gemm_o: out = att(fp16) @ wot(fp16) + bo. (unchanged from R16)
// ---------------------------------------------------------------------------
__global__ __launch_bounds__(256) void gemm_o(
    const unsigned short* __restrict__ attb, const unsigned short* __restrict__ wot,
    const float* __restrict__ bo, float* __restrict__ out)
{
    const int m0 = blockIdx.x * 128;
    const int n0 = blockIdx.y * 128;
    const int tid = threadIdx.x;
    const int lane = tid & 63, w = tid >> 6;
    const int wr = w >> 1, wc = w & 1;
    const int fla = lane & 15, flb = lane >> 4;

    __shared__ unsigned short As[4096];
    __shared__ unsigned short Bs[4096];

    f32x4 acc[4][4];
#pragma unroll
    for (int i=0;i<4;i++)
#pragma unroll
        for (int j=0;j<4;j++) acc[i][j] = (f32x4){0.f,0.f,0.f,0.f};

    const int srow0 = w*32 + (lane>>2);
    const int srow1 = srow0 + 16;
    const int spc   = lane & 3;
    const size_t ga0 = (size_t)(m0+srow0)*1024 + (size_t)((spc ^ ((srow0>>1)&3))*8);
    const size_t ga1 = (size_t)(m0+srow1)*1024 + (size_t)((spc ^ ((srow1>>1)&3))*8);
    const size_t gb0 = (size_t)(n0+srow0)*1024 + (size_t)((spc ^ ((srow0>>1)&3))*8);
    const size_t gb1 = (size_t)(n0+srow1)*1024 + (size_t)((spc ^ ((srow1>>1)&3))*8);
    const int ldso0 = w*1024;
    const int ldso1 = w*1024 + 512;
    const int pchunk = (flb ^ ((fla>>1)&3)) * 8;

    for (int ks = 0; ks < 32; ++ks){
        const size_t k0 = (size_t)ks*32;
        __syncthreads();
        gload_lds16(attb + ga0 + k0, As + ldso0);
        gload_lds16(attb + ga1 + k0, As + ldso1);
        gload_lds16(wot  + gb0 + k0, Bs + ldso0);
        gload_lds16(wot  + gb1 + k0, Bs + ldso1);
        __syncthreads();

        f16x8 af[4], bfr[4];
#pragma unroll
        for (int mf=0; mf<4; ++mf)
            af[mf] = *(const f16x8*)&As[(wr*64+mf*16+fla)*32 + pchunk];
#pragma unroll
        for (int nf=0; nf<4; ++nf)
            bfr[nf] = *(const f16x8*)&Bs[(wc*64+nf*16+fla)*32 + pchunk];
#pragma unroll
        for (int mf=0; mf<4; ++mf)
#pragma unroll
            for (int nf=0; nf<4; ++nf)
                acc[mf][nf] = __builtin_amdgcn_mfma_f32_16x16x32_f16(
                                  af[mf], bfr[nf], acc[mf][nf], 0, 0, 0);
    }

#pragma unroll
    for (int nf=0; nf<4; ++nf){
        const int n = n0 + wc*64 + nf*16 + fla;
        const float bias = bo[n];
#pragma unroll
        for (int mf=0; mf<4; ++mf){
#pragma unroll
            for (int ri=0; ri<4; ++ri){
                const int m = m0 + wr*64 + mf*16 + flb*4 + ri;
                out[(size_t)m*D_ + n] = acc[mf][nf][ri] + bias;
            }
        }
    }
}

// ---------------------------------------------------------------------------
// MFMA flash attention, fp16, exp2-domain, KVBLK=128.
// One softmax pass / pmax-reduce / defer-check / 2 barriers per 128 keys;
// softmax denominator kept as per-lane partial, reduced once after the loop.
// LDS: chunk-XOR layouts KS[2][128][32] + VtS[4][64][32] + PsS[4][64][32]
// = 48KB -> 3 blocks/CU.
// ---------------------------------------------------------------------------
__global__ __launch_bounds__(256) void attn_mfma(
    const unsigned short* __restrict__ qp, const unsigned short* __restrict__ kp,
    const unsigned short* __restrict__ vtp, unsigned short* __restrict__ attb,
    const int* __restrict__ maskp)
{
    const int bid = blockIdx.x;
    const int qb  = 31 - (bid >> 6);   // big blocks first
    const int bh  = bid & 63;
    const int b   = bh >> 4, h = bh & 15;
    const int tid = threadIdx.x;
    const int lane = tid & 63, w = tid >> 6;
    const int l16 = lane & 15, h16 = lane >> 4;
    const int domask = maskp[0];

    __shared__ unsigned short KS [2][128][32];   // [d-half][key][d%32]
    __shared__ unsigned short VtS[4][64][32];    // [key-chunk][d][key%32]
    __shared__ unsigned short PsS[4][64][32];    // [key-chunk][q][key%32]

    const int qrow = qb*64 + w*16 + l16;
    const size_t qoff = ((size_t)bh*T_ + qrow)*HD_ + 8*h16;
    const f16x8 q0 = *(const f16x8*)(qp + qoff);
    const f16x8 q1 = *(const f16x8*)(qp + qoff + 32);

    f32x4 accO[4];
#pragma unroll
    for (int j=0;j<4;j++) accO[j] = (f32x4){0.f,0.f,0.f,0.f};
    float m_run[4], lpart[4];
#pragma unroll
    for (int i=0;i<4;i++){ m_run[i] = -INFINITY; lpart[i] = 0.f; }

    // staging geometry
    const int kr = tid >> 1;          // 0..127 key row (K)
    const int kh = tid & 1;           // d-half (K)
    const int fk = (kr >> 1) & 3;
    const int vr = tid >> 2;          // 0..63 d row (V)
    const int vq = tid & 3;           // key quarter (V)
    const int fv = (vr >> 1) & 3;

    // fragment-read swizzle: all fragment rows == l16 (mod 16)
    const int off = (h16 ^ ((l16>>1)&3)) * 8;

    const size_t kbase = (size_t)bh*T_*HD_;
    const size_t vbase = (size_t)bh*HD_*T_;

    const int nchunks = domask ? ((qb+2)>>1) : 16;   // ceil((qb+1)/2)
    for (int ci = 0; ci < nchunks; ++ci){
        const int kb = ci << 7;
        const unsigned short* ksrc = kp + kbase + (size_t)(kb+kr)*HD_ + kh*32;
        uint4 ka0=*(const uint4*)(ksrc),    ka1=*(const uint4*)(ksrc+8);
        uint4 ka2=*(const uint4*)(ksrc+16), ka3=*(const uint4*)(ksrc+24);
        const unsigned short* vsrc = vtp + vbase + (size_t)vr*T_ + kb + vq*32;
        uint4 va0=*(const uint4*)(vsrc),    va1=*(const uint4*)(vsrc+8);
        uint4 va2=*(const uint4*)(vsrc+16), va3=*(const uint4*)(vsrc+24);
        __syncthreads();   // prev chunk's LDS reads complete
        *(uint4*)&KS [kh][kr][(0^fk)*8] = ka0;
        *(uint4*)&KS [kh][kr][(1^fk)*8] = ka1;
        *(uint4*)&KS [kh][kr][(2^fk)*8] = ka2;
        *(uint4*)&KS [kh][kr][(3^fk)*8] = ka3;
        *(uint4*)&VtS[vq][vr][(0^fv)*8] = va0;
        *(uint4*)&VtS[vq][vr][(1^fv)*8] = va1;
        *(uint4*)&VtS[vq][vr][(2^fv)*8] = va2;
        *(uint4*)&VtS[vq][vr][(3^fv)*8] = va3;
        __syncthreads();

        // S = Q K^T (8 key-blocks of 16)
        f32x4 s[8];
#pragma unroll
        for (int j=0;j<8;j++){
            const f16x8 k0 = *(const f16x8*)&KS[0][j*16+l16][off];
            const f16x8 k1 = *(const f16x8*)&KS[1][j*16+l16][off];
            f32x4 a = (f32x4){0.f,0.f,0.f,0.f};
            a = __builtin_amdgcn_mfma_f32_16x16x32_f16(q0, k0, a, 0,0,0);
            a = __builtin_amdgcn_mfma_f32_16x16x32_f16(q1, k1, a, 0,0,0);
            s[j] = a;
        }
        if (domask && ci == nchunks-1){
#pragma unroll
            for (int j=0;j<8;j++)
#pragma unroll
                for (int reg=0;reg<4;reg++)
                    if (kb + j*16 + l16 > qb*64 + w*16 + h16*4 + reg)
                        s[j][reg] = -INFINITY;
        }

        // row maxima (one reduce per 128 keys)
        float pmax[4];
#pragma unroll
        for (int reg=0; reg<4; ++reg){
            float m0 = fmaxf(fmaxf(s[0][reg],s[1][reg]), fmaxf(s[2][reg],s[3][reg]));
            float m1 = fmaxf(fmaxf(s[4][reg],s[5][reg]), fmaxf(s[6][reg],s[7][reg]));
            float mloc = fmaxf(m0, m1);
            mloc = fmaxf(mloc, __shfl_xor(mloc,1));
            mloc = fmaxf(mloc, __shfl_xor(mloc,2));
            mloc = fmaxf(mloc, __shfl_xor(mloc,4));
            mloc = fmaxf(mloc, __shfl_xor(mloc,8));
            pmax[reg] = mloc;
        }
        // defer-max: skip rescale when growth <= 8 (log2 units -> P <= 256)
        const bool small = (pmax[0] <= m_run[0]+8.f) && (pmax[1] <= m_run[1]+8.f)
                        && (pmax[2] <= m_run[2]+8.f) && (pmax[3] <= m_run[3]+8.f);
        if (!__all(small)){
#pragma unroll
            for (int reg=0; reg<4; ++reg){
                const float mnew = fmaxf(m_run[reg], pmax[reg]);
                const float scl  = exp2f(m_run[reg] - mnew);  // 0 on first chunk
                m_run[reg] = mnew;
                lpart[reg] *= scl;
                accO[0][reg] *= scl; accO[1][reg] *= scl;
                accO[2][reg] *= scl; accO[3][reg] *= scl;
            }
        }

        // P = exp2(S - m); per-lane partial sums; swizzled scalar stores
        const int sblo = l16 >> 3, pos = l16 & 7;
#pragma unroll
        for (int reg=0; reg<4; ++reg){
            const float mr = m_run[reg];
            const int prow = w*16 + h16*4 + reg;
            const int psw  = (prow>>1)&3;
            float ps = 0.f;
#pragma unroll
            for (int j=0;j<8;j++){
                const float p = exp2f(s[j][reg]-mr);
                ps += p;
                PsS[j>>1][prow][(((j&1)*2 + sblo) ^ psw)*8 + pos] = f2h(p);
            }
            lpart[reg] += ps;
        }

        // O += P V (PsS rows wave-private; same-wave RAW via lgkmcnt)
#pragma unroll
        for (int kc=0;kc<4;kc++){
            const f16x8 pa = *(const f16x8*)&PsS[kc][w*16+l16][off];
#pragma unroll
            for (int j=0;j<4;j++){
                const f16x8 vb_ = *(const f16x8*)&VtS[kc][j*16+l16][off];
                accO[j] = __builtin_amdgcn_mfma_f32_16x16x32_f16(pa, vb_, accO[j], 0,0,0);
            }
        }
    }

    // final cross-lane denominator reduce + output
#pragma unroll
    for (int reg=0;reg<4;reg++){
        float l = lpart[reg];
        l += __shfl_xor(l,1); l += __shfl_xor(l,2);
        l += __shfl_xor(l,4); l += __shfl_xor(l,8);
        const float inv = 1.0f / l;
        const int t = qb*64 + w*16 + h16*4 + reg;
#pragma unroll
        for (int j=0;j<4;j++){
            attb[((size_t)b*T_ + t)*D_ + h*HD_ + j*16 + l16] =
                f2h(accO[j][reg]*inv);
        }
    }
}

extern "C" void kernel_launch(void* const* d_in, const int* in_sizes, int n_in,
                              void* d_out, int out_size, void* d_ws, size_t ws_size,
                              hipStream_t stream)
{
    const float* x  = (const float*)d_in[0];
    const float* Wq = (const float*)d_in[1];
    const float* bq = (const float*)d_in[2];
    const float* Wk = (const float*)d_in[3];
    const float* bk = (const float*)d_in[4];
    const float* Wv = (const float*)d_in[5];
    const float* bv = (const float*)d_in[6];
    const float* Wo = (const float*)d_in[7];
    const float* bo = (const float*)d_in[8];
    const int* mask = (const int*)d_in[9];
    float* out = (float*)d_out;

    // workspace (72 MiB): all fp16
    unsigned short* qp  = (unsigned short*)d_ws;                 // 16 MiB
    unsigned short* kp  = qp  + (size_t)8*1024*1024;             // 16 MiB
    unsigned short* vtp = kp  + (size_t)8*1024*1024;             // 16 MiB [bh][d][t]
    unsigned short* xb  = vtp + (size_t)8*1024*1024;             // 16 MiB
    unsigned short* wt  = xb  + (size_t)8*1024*1024;             // 6 MiB
    unsigned short* wot = wt  + (size_t)3*1024*1024;             // 2 MiB
    unsigned short* attb = xb;   // alias: xb dead after gemm_qkvh

    prep_xh   <<<2048, 256, 0, stream>>>(x, xb);
    prep_wqkvh<<<dim3(16,48), 256, 0, stream>>>(Wq, Wk, Wv, wt);
    prep_woh  <<<dim3(16,16), 256, 0, stream>>>(Wo, wot);
    gemm_qkvh <<<dim3(64,24), 256, 0, stream>>>(xb, wt, bq, bk, bv, qp, kp, vtp);
    attn_mfma <<<2048, 256, 0, stream>>>(qp, kp, vtp, attb, mask);
    gemm_o    <<<dim3(64,8), 256, 0, stream>>>(attb, wot, bo, out);
}

// Round 20
// 189.104 us; speedup vs baseline: 2.2194x; 1.0755x over previous
//
#include <hip/hip_runtime.h>
#include <hip/hip_bf16.h>
#include <math.h>

#define B_  4
#define T_  2048
#define D_  1024
#define H_  16
#define HD_ 64
#define M_  8192   // B_*T_

typedef __attribute__((ext_vector_type(8))) _Float16 f16x8;
typedef __attribute__((ext_vector_type(2))) __fp16  h16x2;
typedef __attribute__((ext_vector_type(4))) float   f32x4;

static __device__ __forceinline__ unsigned short f2h(float f){
    union { _Float16 h; unsigned short u; } cv; cv.h = (_Float16)f; return cv.u;
}
static __device__ __forceinline__ unsigned int pkh2(float a, float b){
    union { h16x2 h; unsigned int u; } cv;
    cv.h = __builtin_amdgcn_cvt_pkrtz(a, b);
    return cv.u;
}
static __device__ __forceinline__ void gload_lds16(const void* g, void* l){
    __builtin_amdgcn_global_load_lds(
        (const __attribute__((address_space(1))) unsigned int*)g,
        (__attribute__((address_space(3))) unsigned int*)l, 16, 0, 0);
}

union U16x16 { unsigned short us[16]; uint4 q[2]; };
union U16x4  { unsigned short us[4];  uint2 q;    };

// ---------------------------------------------------------------------------
// prep_xh: x fp32 [8192][1024] -> xb fp16. 16 el/thread.
// ---------------------------------------------------------------------------
__global__ __launch_bounds__(256) void prep_xh(
    const float* __restrict__ x, unsigned short* __restrict__ xb)
{
    const size_t i = ((size_t)blockIdx.x*256 + threadIdx.x)*16;
    U16x16 u;
#pragma unroll
    for (int j=0;j<16;j+=4){
        float4 f = *(const float4*)(x+i+j);
        u.us[j+0]=f2h(f.x); u.us[j+1]=f2h(f.y);
        u.us[j+2]=f2h(f.z); u.us[j+3]=f2h(f.w);
    }
    *(uint4*)(xb+i)   = u.q[0];
    *(uint4*)(xb+i+8) = u.q[1];
}

// ---------------------------------------------------------------------------
// prep_wqkvh: W{q,k,v}[16][1024][64] -> wt[3072][1024] fp16 (operand-major).
// ---------------------------------------------------------------------------
__global__ __launch_bounds__(256) void prep_wqkvh(
    const float* __restrict__ Wq, const float* __restrict__ Wk,
    const float* __restrict__ Wv, unsigned short* __restrict__ wt)
{
    const int dt = blockIdx.x;
    const int zh = blockIdx.y;
    const int z = zh >> 4, h = zh & 15;
    const float* src = ((z==0)?Wq:(z==1)?Wk:Wv) + (size_t)h*1024*64;
    __shared__ float Tt[64][68];
    const int t = threadIdx.x;
    const int r = t >> 2, c4 = (t & 3) * 16;
    const float* sp = src + (size_t)(dt*64 + r)*64 + c4;
    float4 v0=*(const float4*)(sp+0), v1=*(const float4*)(sp+4);
    float4 v2=*(const float4*)(sp+8), v3=*(const float4*)(sp+12);
    *(float4*)&Tt[r][c4+ 0]=v0; *(float4*)&Tt[r][c4+ 4]=v1;
    *(float4*)&Tt[r][c4+ 8]=v2; *(float4*)&Tt[r][c4+12]=v3;
    __syncthreads();
    const int er = t >> 2, dk = (t & 3) * 16;
    U16x16 u;
#pragma unroll
    for (int j=0;j<16;j++) u.us[j] = f2h(Tt[dk+j][er]);
    unsigned short* dst = wt + (size_t)(z*1024 + h*64 + er)*1024 + dt*64 + dk;
    *(uint4*)(dst)   = u.q[0];
    *(uint4*)(dst+8) = u.q[1];
}

// ---------------------------------------------------------------------------
// prep_woh: Wo[1024][1024] -> wot[n][k] fp16.
// ---------------------------------------------------------------------------
__global__ __launch_bounds__(256) void prep_woh(
    const float* __restrict__ Wo, unsigned short* __restrict__ wot)
{
    const int kt = blockIdx.x, nt = blockIdx.y;
    __shared__ float Tt[64][68];
    const int t = threadIdx.x;
    const int r = t >> 2, c4 = (t & 3) * 16;
    const float* sp = Wo + (size_t)(kt*64 + r)*1024 + nt*64 + c4;
    float4 v0=*(const float4*)(sp+0), v1=*(const float4*)(sp+4);
    float4 v2=*(const float4*)(sp+8), v3=*(const float4*)(sp+12);
    *(float4*)&Tt[r][c4+ 0]=v0; *(float4*)&Tt[r][c4+ 4]=v1;
    *(float4*)&Tt[r][c4+ 8]=v2; *(float4*)&Tt[r][c4+12]=v3;
    __syncthreads();
    const int er = t >> 2, dk = (t & 3) * 16;
    U16x16 u;
#pragma unroll
    for (int j=0;j<16;j++) u.us[j] = f2h(Tt[dk+j][er]);
    unsigned short* dst = wot + (size_t)(nt*64 + er)*1024 + kt*64 + dk;
    *(uint4*)(dst)   = u.q[0];
    *(uint4*)(dst+8) = u.q[1];
}

// ---------------------------------------------------------------------------
// gemm_qkvh: unchanged (q scale folds 8*log2(e)).
// ---------------------------------------------------------------------------
__global__ __launch_bounds__(256) void gemm_qkvh(
    const unsigned short* __restrict__ xb, const unsigned short* __restrict__ wt,
    const float* __restrict__ bqv, const float* __restrict__ bkv,
    const float* __restrict__ bvv,
    unsigned short* __restrict__ qp, unsigned short* __restrict__ kp,
    unsigned short* __restrict__ vtp)
{
    const int m0 = blockIdx.x * 128;
    const int n0 = blockIdx.y * 128;
    const int tid = threadIdx.x;
    const int lane = tid & 63, w = tid >> 6;
    const int wr = w >> 1, wc = w & 1;
    const int fla = lane & 15, flb = lane >> 4;

    __shared__ unsigned short As[128*32];
    __shared__ unsigned short Bs[128*32];

    f32x4 acc[4][4];
#pragma unroll
    for (int i=0;i<4;i++)
#pragma unroll
        for (int j=0;j<4;j++) acc[i][j] = (f32x4){0.f,0.f,0.f,0.f};

    const int srow0 = w*32 + (lane>>2);
    const int srow1 = srow0 + 16;
    const int spc   = lane & 3;
    const size_t ga0 = (size_t)(m0+srow0)*1024 + (size_t)((spc ^ ((srow0>>1)&3))*8);
    const size_t ga1 = (size_t)(m0+srow1)*1024 + (size_t)((spc ^ ((srow1>>1)&3))*8);
    const size_t gb0 = (size_t)(n0+srow0)*1024 + (size_t)((spc ^ ((srow0>>1)&3))*8);
    const size_t gb1 = (size_t)(n0+srow1)*1024 + (size_t)((spc ^ ((srow1>>1)&3))*8);
    const int ldso0 = w*1024;          // shorts
    const int ldso1 = w*1024 + 512;
    const int pchunk = (flb ^ ((fla>>1)&3)) * 8;

    for (int ks = 0; ks < 32; ++ks){
        const size_t k0 = (size_t)ks*32;
        __syncthreads();   // prev chunk's fragment reads complete
        gload_lds16(xb + ga0 + k0, As + ldso0);
        gload_lds16(xb + ga1 + k0, As + ldso1);
        gload_lds16(wt + gb0 + k0, Bs + ldso0);
        gload_lds16(wt + gb1 + k0, Bs + ldso1);
        __syncthreads();   // vmcnt(0) drained at barrier

        f16x8 af[4], bfr[4];
#pragma unroll
        for (int mf=0; mf<4; ++mf)
            af[mf] = *(const f16x8*)&As[(wr*64+mf*16+fla)*32 + pchunk];
#pragma unroll
        for (int nf=0; nf<4; ++nf)
            bfr[nf] = *(const f16x8*)&Bs[(wc*64+nf*16+fla)*32 + pchunk];
#pragma unroll
        for (int mf=0; mf<4; ++mf)
#pragma unroll
            for (int nf=0; nf<4; ++nf)
                acc[mf][nf] = __builtin_amdgcn_mfma_f32_16x16x32_f16(
                                  af[mf], bfr[nf], acc[mf][nf], 0, 0, 0);
    }

#pragma unroll
    for (int nf=0; nf<4; ++nf){
        const int c = n0 + wc*64 + nf*16 + fla;
        const int z = c >> 10, rem = c & 1023;
        const int h = rem >> 6, e = rem & 63;
        if (z < 2){
            const float bias = ((z==0)?bqv:bkv)[rem];
            const float scl  = (z==0) ? 11.541560327111708f   // 8*log2(e)
                                      : 1.0f;
            unsigned short* op = (z==0)?qp:kp;
#pragma unroll
            for (int mf=0; mf<4; ++mf){
#pragma unroll
                for (int ri=0; ri<4; ++ri){
                    const int m = m0 + wr*64 + mf*16 + flb*4 + ri;
                    const int b = m >> 11, t = m & (T_-1);
                    op[((size_t)(b*H_ + h)*T_ + t)*HD_ + e] =
                        f2h((acc[mf][nf][ri] + bias) * scl);
                }
            }
        } else {
            const float bias = bvv[rem];
#pragma unroll
            for (int mf=0; mf<4; ++mf){
                const int m = m0 + wr*64 + mf*16 + flb*4;   // 4 consecutive t
                const int b = m >> 11, t = m & (T_-1);
                U16x4 u;
#pragma unroll
                for (int ri=0; ri<4; ++ri)
                    u.us[ri] = f2h(acc[mf][nf][ri] + bias);
                *(uint2*)(vtp + ((size_t)(b*H_ + h)*HD_ + e)*T_ + t) = u.q;
            }
        }
    }
}

// ---------------------------------------------------------------------------
// gemm_o: out = att(fp16) @ wot(fp16) + bo. (unchanged)
// ---------------------------------------------------------------------------
__global__ __launch_bounds__(256) void gemm_o(
    const unsigned short* __restrict__ attb, const unsigned short* __restrict__ wot,
    const float* __restrict__ bo, float* __restrict__ out)
{
    const int m0 = blockIdx.x * 128;
    const int n0 = blockIdx.y * 128;
    const int tid = threadIdx.x;
    const int lane = tid & 63, w = tid >> 6;
    const int wr = w >> 1, wc = w & 1;
    const int fla = lane & 15, flb = lane >> 4;

    __shared__ unsigned short As[4096];
    __shared__ unsigned short Bs[4096];

    f32x4 acc[4][4];
#pragma unroll
    for (int i=0;i<4;i++)
#pragma unroll
        for (int j=0;j<4;j++) acc[i][j] = (f32x4){0.f,0.f,0.f,0.f};

    const int srow0 = w*32 + (lane>>2);
    const int srow1 = srow0 + 16;
    const int spc   = lane & 3;
    const size_t ga0 = (size_t)(m0+srow0)*1024 + (size_t)((spc ^ ((srow0>>1)&3))*8);
    const size_t ga1 = (size_t)(m0+srow1)*1024 + (size_t)((spc ^ ((srow1>>1)&3))*8);
    const size_t gb0 = (size_t)(n0+srow0)*1024 + (size_t)((spc ^ ((srow0>>1)&3))*8);
    const size_t gb1 = (size_t)(n0+srow1)*1024 + (size_t)((spc ^ ((srow1>>1)&3))*8);
    const int ldso0 = w*1024;
    const int ldso1 = w*1024 + 512;
    const int pchunk = (flb ^ ((fla>>1)&3)) * 8;

    for (int ks = 0; ks < 32; ++ks){
        const size_t k0 = (size_t)ks*32;
        __syncthreads();
        gload_lds16(attb + ga0 + k0, As + ldso0);
        gload_lds16(attb + ga1 + k0, As + ldso1);
        gload_lds16(wot  + gb0 + k0, Bs + ldso0);
        gload_lds16(wot  + gb1 + k0, Bs + ldso1);
        __syncthreads();

        f16x8 af[4], bfr[4];
#pragma unroll
        for (int mf=0; mf<4; ++mf)
            af[mf] = *(const f16x8*)&As[(wr*64+mf*16+fla)*32 + pchunk];
#pragma unroll
        for (int nf=0; nf<4; ++nf)
            bfr[nf] = *(const f16x8*)&Bs[(wc*64+nf*16+fla)*32 + pchunk];
#pragma unroll
        for (int mf=0; mf<4; ++mf)
#pragma unroll
            for (int nf=0; nf<4; ++nf)
                acc[mf][nf] = __builtin_amdgcn_mfma_f32_16x16x32_f16(
                                  af[mf], bfr[nf], acc[mf][nf], 0, 0, 0);
    }

#pragma unroll
    for (int nf=0; nf<4; ++nf){
        const int n = n0 + wc*64 + nf*16 + fla;
        const float bias = bo[n];
#pragma unroll
        for (int mf=0; mf<4; ++mf){
#pragma unroll
            for (int ri=0; ri<4; ++ri){
                const int m = m0 + wr*64 + mf*16 + flb*4 + ri;
                out[(size_t)m*D_ + n] = acc[mf][nf][ri] + bias;
            }
        }
    }
}

// ---------------------------------------------------------------------------
// MFMA flash attention, fp16, exp2-domain, KVBLK=128, SWAPPED QK^T:
// s = mfma(K, Q) -> lane's D col (l16) = q-row, rows (4*h16+reg) = keys.
// Softmax row state (m, lpart) is SCALAR per lane; row-max = 31 in-lane fmax
// + 2 shfl_xor(16,32). P packed via v_cvt_pkrtz (consecutive keys per lane),
// stored as b32 pairs. accO (rows keyed by 4h16+reg) rescale/normalize pulls
// per-row factors via 4 __shfl (rare / once).
// LDS: KS[2][128][32] + VtS[4][64][32] + PsS[4][64][32] = 48KB.
// ---------------------------------------------------------------------------
__global__ __launch_bounds__(256) void attn_mfma(
    const unsigned short* __restrict__ qp, const unsigned short* __restrict__ kp,
    const unsigned short* __restrict__ vtp, unsigned short* __restrict__ attb,
    const int* __restrict__ maskp)
{
    const int bid = blockIdx.x;
    const int qb  = 31 - (bid >> 6);   // big blocks first
    const int bh  = bid & 63;
    const int b   = bh >> 4, h = bh & 15;
    const int tid = threadIdx.x;
    const int lane = tid & 63, w = tid >> 6;
    const int l16 = lane & 15, h16 = lane >> 4;
    const int domask = maskp[0];

    __shared__ unsigned short KS [2][128][32];   // [d-half][key][d%32]
    __shared__ unsigned short VtS[4][64][32];    // [key-chunk][d][key%32]
    __shared__ unsigned short PsS[4][64][32];    // [key-chunk][q][key%32]

    const int qrow = qb*64 + w*16 + l16;         // this lane's softmax row
    const size_t qoff = ((size_t)bh*T_ + qrow)*HD_ + 8*h16;
    const f16x8 q0 = *(const f16x8*)(qp + qoff);
    const f16x8 q1 = *(const f16x8*)(qp + qoff + 32);

    f32x4 accO[4];
#pragma unroll
    for (int j=0;j<4;j++) accO[j] = (f32x4){0.f,0.f,0.f,0.f};
    float m_run = -INFINITY, lpart = 0.f;

    // staging geometry
    const int kr = tid >> 1;          // 0..127 key row (K)
    const int kh = tid & 1;           // d-half (K)
    const int fk = (kr >> 1) & 3;
    const int vr = tid >> 2;          // 0..63 d row (V)
    const int vq = tid & 3;           // key quarter (V)
    const int fv = (vr >> 1) & 3;

    // fragment-read swizzle (all fragment rows == l16 mod 16)
    const int off = (h16 ^ ((l16>>1)&3)) * 8;
    const int psw = (l16>>1)&3;       // P-row swizzle key (row = w*16+l16)

    const size_t kbase = (size_t)bh*T_*HD_;
    const size_t vbase = (size_t)bh*HD_*T_;

    const int nchunks = domask ? ((qb+2)>>1) : 16;   // ceil((qb+1)/2)
    for (int ci = 0; ci < nchunks; ++ci){
        const int kb = ci << 7;
        const unsigned short* ksrc = kp + kbase + (size_t)(kb+kr)*HD_ + kh*32;
        uint4 ka0=*(const uint4*)(ksrc),    ka1=*(const uint4*)(ksrc+8);
        uint4 ka2=*(const uint4*)(ksrc+16), ka3=*(const uint4*)(ksrc+24);
        const unsigned short* vsrc = vtp + vbase + (size_t)vr*T_ + kb + vq*32;
        uint4 va0=*(const uint4*)(vsrc),    va1=*(const uint4*)(vsrc+8);
        uint4 va2=*(const uint4*)(vsrc+16), va3=*(const uint4*)(vsrc+24);
        __syncthreads();   // prev chunk's LDS reads complete
        *(uint4*)&KS [kh][kr][(0^fk)*8] = ka0;
        *(uint4*)&KS [kh][kr][(1^fk)*8] = ka1;
        *(uint4*)&KS [kh][kr][(2^fk)*8] = ka2;
        *(uint4*)&KS [kh][kr][(3^fk)*8] = ka3;
        *(uint4*)&VtS[vq][vr][(0^fv)*8] = va0;
        *(uint4*)&VtS[vq][vr][(1^fv)*8] = va1;
        *(uint4*)&VtS[vq][vr][(2^fv)*8] = va2;
        *(uint4*)&VtS[vq][vr][(3^fv)*8] = va3;
        __syncthreads();

        // S^T = K Q : s[j][reg] = S[qrow][key = kb + 16j + 4*h16 + reg]
        f32x4 s[8];
#pragma unroll
        for (int j=0;j<8;j++){
            const f16x8 k0 = *(const f16x8*)&KS[0][j*16+l16][off];
            const f16x8 k1 = *(const f16x8*)&KS[1][j*16+l16][off];
            f32x4 a = (f32x4){0.f,0.f,0.f,0.f};
            a = __builtin_amdgcn_mfma_f32_16x16x32_f16(k0, q0, a, 0,0,0);
            a = __builtin_amdgcn_mfma_f32_16x16x32_f16(k1, q1, a, 0,0,0);
            s[j] = a;
        }
        if (domask && ci == nchunks-1){
#pragma unroll
            for (int j=0;j<8;j++)
#pragma unroll
                for (int reg=0;reg<4;reg++)
                    if (kb + j*16 + 4*h16 + reg > qrow)
                        s[j][reg] = -INFINITY;
        }

        // row max: 31 in-lane fmax (tree) + 2 cross-lane
        float mx01 = fmaxf(fmaxf(s[0][0],s[0][1]), fmaxf(s[0][2],s[0][3]));
        float mx1  = fmaxf(fmaxf(s[1][0],s[1][1]), fmaxf(s[1][2],s[1][3]));
        float mx2  = fmaxf(fmaxf(s[2][0],s[2][1]), fmaxf(s[2][2],s[2][3]));
        float mx3  = fmaxf(fmaxf(s[3][0],s[3][1]), fmaxf(s[3][2],s[3][3]));
        float mx4  = fmaxf(fmaxf(s[4][0],s[4][1]), fmaxf(s[4][2],s[4][3]));
        float mx5  = fmaxf(fmaxf(s[5][0],s[5][1]), fmaxf(s[5][2],s[5][3]));
        float mx6  = fmaxf(fmaxf(s[6][0],s[6][1]), fmaxf(s[6][2],s[6][3]));
        float mx7  = fmaxf(fmaxf(s[7][0],s[7][1]), fmaxf(s[7][2],s[7][3]));
        float mloc = fmaxf(fmaxf(fmaxf(mx01,mx1), fmaxf(mx2,mx3)),
                           fmaxf(fmaxf(mx4,mx5), fmaxf(mx6,mx7)));
        mloc = fmaxf(mloc, __shfl_xor(mloc,16));
        mloc = fmaxf(mloc, __shfl_xor(mloc,32));

        // defer-max: skip rescale when growth <= 8 (log2 units -> P <= 256)
        const bool small = (mloc <= m_run + 8.f);
        if (!__all(small)){
            const float mnew = fmaxf(m_run, mloc);
            const float scl  = exp2f(m_run - mnew);   // 0 on first chunk
            m_run = mnew;
            lpart *= scl;
            // accO rows are qrow-local 4*h16+reg -> gather their scales
            const float sr0 = __shfl(scl, 4*h16+0);
            const float sr1 = __shfl(scl, 4*h16+1);
            const float sr2 = __shfl(scl, 4*h16+2);
            const float sr3 = __shfl(scl, 4*h16+3);
#pragma unroll
            for (int j=0;j<4;j++){
                accO[j][0] *= sr0; accO[j][1] *= sr1;
                accO[j][2] *= sr2; accO[j][3] *= sr3;
            }
        }

        // P = exp2(S - m); pack consecutive-key pairs; b32 swizzled stores
        const int prow = w*16 + l16;
        float ps = 0.f;
#pragma unroll
        for (int j=0;j<8;j++){
            const float p0 = exp2f(s[j][0]-m_run);
            const float p1 = exp2f(s[j][1]-m_run);
            const float p2 = exp2f(s[j][2]-m_run);
            const float p3 = exp2f(s[j][3]-m_run);
            ps += (p0+p1)+(p2+p3);
            const unsigned int u01 = pkh2(p0,p1);
            const unsigned int u23 = pkh2(p2,p3);
            const int sb = 2*(j&1) + (h16>>1);
            const int so = ((sb ^ psw)<<3) + 4*(h16&1);
            *(unsigned int*)&PsS[j>>1][prow][so]   = u01;
            *(unsigned int*)&PsS[j>>1][prow][so+2] = u23;
        }
        lpart += ps;

        // O += P V (PsS rows wave-private; same-wave RAW via lgkmcnt)
#pragma unroll
        for (int kc=0;kc<4;kc++){
            const f16x8 pa = *(const f16x8*)&PsS[kc][w*16+l16][off];
#pragma unroll
            for (int j=0;j<4;j++){
                const f16x8 vb_ = *(const f16x8*)&VtS[kc][j*16+l16][off];
                accO[j] = __builtin_amdgcn_mfma_f32_16x16x32_f16(pa, vb_, accO[j], 0,0,0);
            }
        }
    }

    // final denominator: reduce across the 4 lanes sharing this q-row,
    // then redistribute to accO's row keying (4*h16+reg)
    float l = lpart;
    l += __shfl_xor(l,16); l += __shfl_xor(l,32);
    const float inv = 1.0f / l;
    const float ir0 = __shfl(inv, 4*h16+0);
    const float ir1 = __shfl(inv, 4*h16+1);
    const float ir2 = __shfl(inv, 4*h16+2);
    const float ir3 = __shfl(inv, 4*h16+3);
    const int t0 = qb*64 + w*16 + 4*h16;
#pragma unroll
    for (int j=0;j<4;j++){
        const size_t base = ((size_t)b*T_ + t0)*D_ + h*HD_ + j*16 + l16;
        attb[base        ] = f2h(accO[j][0]*ir0);
        attb[base +   D_ ] = f2h(accO[j][1]*ir1);
        attb[base + 2*D_ ] = f2h(accO[j][2]*ir2);
        attb[base + 3*D_ ] = f2h(accO[j][3]*ir3);
    }
}

extern "C" void kernel_launch(void* const* d_in, const int* in_sizes, int n_in,
                              void* d_out, int out_size, void* d_ws, size_t ws_size,
                              hipStream_t stream)
{
    const float* x  = (const float*)d_in[0];
    const float* Wq = (const float*)d_in[1];
    const float* bq = (const float*)d_in[2];
    const float* Wk = (const float*)d_in[3];
    const float* bk = (const float*)d_in[4];
    const float* Wv = (const float*)d_in[5];
    const float* bv = (const float*)d_in[6];
    const float* Wo = (const float*)d_in[7];
    const float* bo = (const float*)d_in[8];
    const int* mask = (const int*)d_in[9];
    float* out = (float*)d_out;

    // workspace (72 MiB): all fp16
    unsigned short* qp  = (unsigned short*)d_ws;                 // 16 MiB
    unsigned short* kp  = qp  + (size_t)8*1024*1024;             // 16 MiB
    unsigned short* vtp = kp  + (size_t)8*1024*1024;             // 16 MiB [bh][d][t]
    unsigned short* xb  = vtp + (size_t)8*1024*1024;             // 16 MiB
    unsigned short* wt  = xb  + (size_t)8*1024*1024;             // 6 MiB
    unsigned short* wot = wt  + (size_t)3*1024*1024;             // 2 MiB
    unsigned short* attb = xb;   // alias: xb dead after gemm_qkvh

    prep_xh   <<<2048, 256, 0, stream>>>(x, xb);
    prep_wqkvh<<<dim3(16,48), 256, 0, stream>>>(Wq, Wk, Wv, wt);
    prep_woh  <<<dim3(16,16), 256, 0, stream>>>(Wo, wot);
    gemm_qkvh <<<dim3(64,24), 256, 0, stream>>>(xb, wt, bq, bk, bv, qp, kp, vtp);
    attn_mfma <<<2048, 256, 0, stream>>>(qp, kp, vtp, attb, mask);
    gemm_o    <<<dim3(64,8), 256, 0, stream>>>(attb, wot, bo, out);
}